// Round 1
// baseline (5031.349 us; speedup 1.0000x reference)
//
#include <hip/hip_runtime.h>
#include <cstdint>
#include <cstddef>

#define SS 512
#define BB 64
#define DD 128
#define HH 8
#define HDIM 16
#define FFD 1024
#define NL 6

// ---------------- transpose (S,B,D) -> (B,S,D), writes x0 and h ----------------
__global__ __launch_bounds__(256) void transpose_kernel(const float* __restrict__ src,
                                                        float* __restrict__ x0,
                                                        float* __restrict__ h) {
  int f = blockIdx.x * 256 + threadIdx.x;       // float4 index over B*S*D/4 = 1048576
  int b = f >> 14;                               // / (512*32)
  int rem = f & 16383;
  int s = rem >> 5;
  int d4 = rem & 31;
  const float4 v = ((const float4*)src)[((size_t)s * BB + b) * 32 + d4];
  ((float4*)x0)[f] = v;
  ((float4*)h)[f] = v;
}

// ---------------- per-row reciprocal norm ----------------
__global__ __launch_bounds__(256) void rownorm_kernel(const float* __restrict__ x,
                                                      float* __restrict__ rn) {
  const int wave = threadIdx.x >> 6;
  const int lane = threadIdx.x & 63;
  const size_t row = (size_t)blockIdx.x * 4 + wave;
  const float2 v = ((const float2*)(x + row * DD))[lane];
  float ss = v.x * v.x + v.y * v.y;
  #pragma unroll
  for (int off = 1; off < 64; off <<= 1) ss += __shfl_xor(ss, off);
  if (lane == 0) rn[row] = rsqrtf(ss);
}

// ---------------- generic tiled GEMM: C[m,n] = act(sum_k A[m,k]*B[n,k] + bias[n]) ----------------
template <bool RELU>
__global__ __launch_bounds__(256) void gemm_kernel(const float* __restrict__ A,
                                                   const float* __restrict__ Bm,
                                                   const float* __restrict__ bias,
                                                   float* __restrict__ C,
                                                   int M, int N, int K) {
  __shared__ float As[64][33];
  __shared__ float Bs[64][33];
  const int t = threadIdx.x;
  const int m0 = blockIdx.y * 64;
  const int n0 = blockIdx.x * 64;
  const int tx = t & 15, ty = t >> 4;
  const int lr = t >> 3;          // 0..31
  const int lc = (t & 7) * 4;     // 0..28
  float acc[4][4] = {};
  for (int kt = 0; kt < K; kt += 32) {
    float4 a0 = *(const float4*)(A + (size_t)(m0 + lr) * K + kt + lc);
    float4 a1 = *(const float4*)(A + (size_t)(m0 + 32 + lr) * K + kt + lc);
    float4 b0 = *(const float4*)(Bm + (size_t)(n0 + lr) * K + kt + lc);
    float4 b1 = *(const float4*)(Bm + (size_t)(n0 + 32 + lr) * K + kt + lc);
    __syncthreads();
    As[lr][lc] = a0.x; As[lr][lc+1] = a0.y; As[lr][lc+2] = a0.z; As[lr][lc+3] = a0.w;
    As[32+lr][lc] = a1.x; As[32+lr][lc+1] = a1.y; As[32+lr][lc+2] = a1.z; As[32+lr][lc+3] = a1.w;
    Bs[lr][lc] = b0.x; Bs[lr][lc+1] = b0.y; Bs[lr][lc+2] = b0.z; Bs[lr][lc+3] = b0.w;
    Bs[32+lr][lc] = b1.x; Bs[32+lr][lc+1] = b1.y; Bs[32+lr][lc+2] = b1.z; Bs[32+lr][lc+3] = b1.w;
    __syncthreads();
    #pragma unroll 8
    for (int kk = 0; kk < 32; ++kk) {
      float a4[4], b4[4];
      #pragma unroll
      for (int i = 0; i < 4; ++i) a4[i] = As[ty * 4 + i][kk];
      #pragma unroll
      for (int j = 0; j < 4; ++j) b4[j] = Bs[tx * 4 + j][kk];
      #pragma unroll
      for (int i = 0; i < 4; ++i)
        #pragma unroll
        for (int j = 0; j < 4; ++j) acc[i][j] = fmaf(a4[i], b4[j], acc[i][j]);
    }
  }
  #pragma unroll
  for (int i = 0; i < 4; ++i) {
    const int m = m0 + ty * 4 + i;
    float4 v;
    float* pv = &v.x;
    #pragma unroll
    for (int j = 0; j < 4; ++j) {
      float c = acc[i][j] + bias[n0 + tx * 4 + j];
      if (RELU) c = fmaxf(c, 0.0f);
      pv[j] = c;
    }
    *(float4*)(C + (size_t)m * N + n0 + tx * 4) = v;
  }
}

// ---------------- batched cosine-sim GEMM ----------------
// MODE 0: out = max(dot * rn_i * rn_j, 1e-6)
// MODE 1: out = clip(0.5*(max(dot,1e-6) + out_prev), 0.1, 0.9)
template <int MODE>
__global__ __launch_bounds__(256) void cos_kernel(const float* __restrict__ X,
                                                  const float* __restrict__ rn,
                                                  float* __restrict__ out) {
  const int b = blockIdx.z;
  const float* Xb = X + (size_t)b * SS * DD;
  __shared__ float As[64][33];
  __shared__ float Bs[64][33];
  const int t = threadIdx.x;
  const int i0 = blockIdx.y * 64;
  const int j0 = blockIdx.x * 64;
  const int tx = t & 15, ty = t >> 4;
  const int lr = t >> 3;
  const int lc = (t & 7) * 4;
  float acc[4][4] = {};
  for (int kt = 0; kt < DD; kt += 32) {
    float4 a0 = *(const float4*)(Xb + (size_t)(i0 + lr) * DD + kt + lc);
    float4 a1 = *(const float4*)(Xb + (size_t)(i0 + 32 + lr) * DD + kt + lc);
    float4 b0 = *(const float4*)(Xb + (size_t)(j0 + lr) * DD + kt + lc);
    float4 b1 = *(const float4*)(Xb + (size_t)(j0 + 32 + lr) * DD + kt + lc);
    __syncthreads();
    As[lr][lc] = a0.x; As[lr][lc+1] = a0.y; As[lr][lc+2] = a0.z; As[lr][lc+3] = a0.w;
    As[32+lr][lc] = a1.x; As[32+lr][lc+1] = a1.y; As[32+lr][lc+2] = a1.z; As[32+lr][lc+3] = a1.w;
    Bs[lr][lc] = b0.x; Bs[lr][lc+1] = b0.y; Bs[lr][lc+2] = b0.z; Bs[lr][lc+3] = b0.w;
    Bs[32+lr][lc] = b1.x; Bs[32+lr][lc+1] = b1.y; Bs[32+lr][lc+2] = b1.z; Bs[32+lr][lc+3] = b1.w;
    __syncthreads();
    #pragma unroll 8
    for (int kk = 0; kk < 32; ++kk) {
      float a4[4], b4[4];
      #pragma unroll
      for (int i = 0; i < 4; ++i) a4[i] = As[ty * 4 + i][kk];
      #pragma unroll
      for (int j = 0; j < 4; ++j) b4[j] = Bs[tx * 4 + j][kk];
      #pragma unroll
      for (int i = 0; i < 4; ++i)
        #pragma unroll
        for (int j = 0; j < 4; ++j) acc[i][j] = fmaf(a4[i], b4[j], acc[i][j]);
    }
  }
  float* ob = out + (size_t)b * SS * SS;
  #pragma unroll
  for (int i = 0; i < 4; ++i) {
    const int ii = i0 + ty * 4 + i;
    float ri = 1.0f;
    if (MODE == 0) ri = rn[b * SS + ii];
    #pragma unroll
    for (int j = 0; j < 4; ++j) {
      const int jj = j0 + tx * 4 + j;
      float v = acc[i][j];
      if (MODE == 0) {
        v = fmaxf(v * ri * rn[b * SS + jj], 1e-6f);
        ob[(size_t)ii * SS + jj] = v;
      } else {
        v = fmaxf(v, 1e-6f);
        float prev = ob[(size_t)ii * SS + jj];
        float r2 = 0.5f * (v + prev);
        r2 = fminf(fmaxf(r2, 0.1f), 0.9f);
        ob[(size_t)ii * SS + jj] = r2;
      }
    }
  }
}

// ---------------- flash-style attention, HD=16, quad-of-threads per q-row ----------------
__global__ __launch_bounds__(256) void attn_kernel(const float* __restrict__ qkv,
                                                   float* __restrict__ o_out) {
  const int qt = blockIdx.x, hh = blockIdx.y, b = blockIdx.z;
  const int t = threadIdx.x;
  const int qr = t >> 2;       // local q row 0..63
  const int ql = t & 3;        // quad lane
  const int qrow = qt * 64 + qr;
  const float* base = qkv + (size_t)b * SS * 384;
  float q[16];
  {
    const float* qp = base + (size_t)qrow * 384 + hh * HDIM;
    #pragma unroll
    for (int i = 0; i < 4; ++i) {
      float4 v = *(const float4*)(qp + i * 4);
      q[i * 4 + 0] = v.x; q[i * 4 + 1] = v.y; q[i * 4 + 2] = v.z; q[i * 4 + 3] = v.w;
    }
  }
  __shared__ float ks[64][17];
  __shared__ float vs[64][17];
  float m = -1e30f, l = 0.0f;
  float o[16];
  #pragma unroll
  for (int d = 0; d < 16; ++d) o[d] = 0.0f;
  const int lr = t >> 2, lc = (t & 3) * 4;
  for (int kt = 0; kt < 8; ++kt) {
    const float* kp = base + (size_t)(kt * 64 + lr) * 384 + DD + hh * HDIM + lc;
    const float4 kv = *(const float4*)kp;
    const float4 vv = *(const float4*)(kp + DD);
    __syncthreads();
    ks[lr][lc] = kv.x; ks[lr][lc+1] = kv.y; ks[lr][lc+2] = kv.z; ks[lr][lc+3] = kv.w;
    vs[lr][lc] = vv.x; vs[lr][lc+1] = vv.y; vs[lr][lc+2] = vv.z; vs[lr][lc+3] = vv.w;
    __syncthreads();
    float s[16];
    float mloc = m;
    #pragma unroll
    for (int j = 0; j < 16; ++j) {
      const float* kr = ks[ql * 16 + j];
      float a = 0.0f;
      #pragma unroll
      for (int d = 0; d < 16; ++d) a = fmaf(q[d], kr[d], a);
      s[j] = a * 0.25f;
      mloc = fmaxf(mloc, s[j]);
    }
    mloc = fmaxf(mloc, __shfl_xor(mloc, 1));
    mloc = fmaxf(mloc, __shfl_xor(mloc, 2));
    const float scale = __expf(m - mloc);
    m = mloc;
    float lsum = 0.0f;
    #pragma unroll
    for (int j = 0; j < 16; ++j) { s[j] = __expf(s[j] - m); lsum += s[j]; }
    l = l * scale + lsum;
    #pragma unroll
    for (int d = 0; d < 16; ++d) o[d] *= scale;
    #pragma unroll
    for (int j = 0; j < 16; ++j) {
      const float p = s[j];
      const float* vr = vs[ql * 16 + j];
      #pragma unroll
      for (int d = 0; d < 16; ++d) o[d] = fmaf(p, vr[d], o[d]);
    }
  }
  l += __shfl_xor(l, 1);
  l += __shfl_xor(l, 2);
  #pragma unroll
  for (int d = 0; d < 16; ++d) { o[d] += __shfl_xor(o[d], 1); o[d] += __shfl_xor(o[d], 2); }
  const float inv = 1.0f / l;
  float4 w;
  w.x = o[ql * 4 + 0] * inv; w.y = o[ql * 4 + 1] * inv;
  w.z = o[ql * 4 + 2] * inv; w.w = o[ql * 4 + 3] * inv;
  *(float4*)(o_out + ((size_t)b * SS + qrow) * DD + hh * HDIM + ql * 4) = w;
}

// ---------------- x = LN(x + r) rowwise ----------------
__global__ __launch_bounds__(256) void add_ln_kernel(float* __restrict__ x,
                                                     const float* __restrict__ r,
                                                     const float* __restrict__ g,
                                                     const float* __restrict__ bb) {
  const int wave = threadIdx.x >> 6;
  const int lane = threadIdx.x & 63;
  const size_t row = (size_t)blockIdx.x * 4 + wave;
  float2 xv = ((const float2*)(x + row * DD))[lane];
  float2 rv = ((const float2*)(r + row * DD))[lane];
  const float a = xv.x + rv.x, c = xv.y + rv.y;
  float sum = a + c;
  #pragma unroll
  for (int off = 1; off < 64; off <<= 1) sum += __shfl_xor(sum, off);
  const float mu = sum * (1.0f / 128.0f);
  const float da = a - mu, dc = c - mu;
  float v = da * da + dc * dc;
  #pragma unroll
  for (int off = 1; off < 64; off <<= 1) v += __shfl_xor(v, off);
  const float rs = rsqrtf(v * (1.0f / 128.0f) + 1e-5f);
  const float2 gv = ((const float2*)g)[lane];
  const float2 bv = ((const float2*)bb)[lane];
  float2 ov;
  ov.x = da * rs * gv.x + bv.x;
  ov.y = dc * rs * gv.y + bv.y;
  ((float2*)(x + row * DD))[lane] = ov;
}

// ---------------- y = normalize(sigmoid(h) * x0) rowwise ----------------
__global__ __launch_bounds__(256) void mask_norm_kernel(const float* __restrict__ h,
                                                        const float* __restrict__ x0,
                                                        float* __restrict__ y) {
  const int wave = threadIdx.x >> 6;
  const int lane = threadIdx.x & 63;
  const size_t row = (size_t)blockIdx.x * 4 + wave;
  const float2 hv = ((const float2*)(h + row * DD))[lane];
  const float2 xv = ((const float2*)(x0 + row * DD))[lane];
  const float a = xv.x / (1.0f + __expf(-hv.x));
  const float c = xv.y / (1.0f + __expf(-hv.y));
  float ss = a * a + c * c;
  #pragma unroll
  for (int off = 1; off < 64; off <<= 1) ss += __shfl_xor(ss, off);
  const float inv = 1.0f / fmaxf(sqrtf(ss), 1e-12f);
  float2 ov; ov.x = a * inv; ov.y = c * inv;
  ((float2*)(y + row * DD))[lane] = ov;
}

extern "C" void kernel_launch(void* const* d_in, const int* in_sizes, int n_in,
                              void* d_out, int out_size, void* d_ws, size_t ws_size,
                              hipStream_t stream) {
  const float* src  = (const float*)d_in[0];
  const float* Wqkv = (const float*)d_in[1];
  const float* bqkv = (const float*)d_in[2];
  const float* Wo   = (const float*)d_in[3];
  const float* bo   = (const float*)d_in[4];
  const float* ln1g = (const float*)d_in[5];
  const float* ln1b = (const float*)d_in[6];
  const float* W1   = (const float*)d_in[7];
  const float* b1   = (const float*)d_in[8];
  const float* W2   = (const float*)d_in[9];
  const float* b2   = (const float*)d_in[10];
  const float* ln2g = (const float*)d_in[11];
  const float* ln2b = (const float*)d_in[12];
  float* out = (float*)d_out;

  float* ws = (float*)d_ws;
  const size_t XSZ = (size_t)BB * SS * DD;      // 4,194,304 floats
  const size_t BIGSZ = (size_t)BB * SS * FFD;   // 33,554,432 floats
  float* x0   = ws;
  float* h    = ws + XSZ;
  float* big  = ws + 2 * XSZ;            // qkv / o2 / ff1
  float* smal = ws + 2 * XSZ + BIGSZ;    // attn-out / f2 / y
  float* rn   = ws + 3 * XSZ + BIGSZ;    // 32768 floats

  const dim3 blk(256);
  const int ROWS = BB * SS;              // 32768

  transpose_kernel<<<4096, blk, 0, stream>>>(src, x0, h);
  rownorm_kernel<<<ROWS / 4, blk, 0, stream>>>(x0, rn);
  cos_kernel<0><<<dim3(8, 8, BB), blk, 0, stream>>>(x0, rn, out);

  for (int l = 0; l < NL; ++l) {
    gemm_kernel<false><<<dim3(6, ROWS / 64), blk, 0, stream>>>(
        h, Wqkv + (size_t)l * 384 * DD, bqkv + l * 384, big, ROWS, 384, DD);
    attn_kernel<<<dim3(8, HH, BB), blk, 0, stream>>>(big, smal);
    gemm_kernel<false><<<dim3(2, ROWS / 64), blk, 0, stream>>>(
        smal, Wo + (size_t)l * DD * DD, bo + l * DD, big, ROWS, DD, DD);
    add_ln_kernel<<<ROWS / 4, blk, 0, stream>>>(h, big, ln1g + l * DD, ln1b + l * DD);
    gemm_kernel<true><<<dim3(16, ROWS / 64), blk, 0, stream>>>(
        h, W1 + (size_t)l * FFD * DD, b1 + l * FFD, big, ROWS, FFD, DD);
    gemm_kernel<false><<<dim3(2, ROWS / 64), blk, 0, stream>>>(
        big, W2 + (size_t)l * DD * FFD, b2 + l * DD, smal, ROWS, DD, FFD);
    add_ln_kernel<<<ROWS / 4, blk, 0, stream>>>(h, smal, ln2g + l * DD, ln2b + l * DD);
  }

  mask_norm_kernel<<<ROWS / 4, blk, 0, stream>>>(h, x0, smal);
  cos_kernel<1><<<dim3(8, 8, BB), blk, 0, stream>>>(smal, nullptr, out);
}

// Round 2
// 3171.702 us; speedup vs baseline: 1.5863x; 1.5863x over previous
//
#include <hip/hip_runtime.h>
#include <cstdint>
#include <cstddef>

#define SS 512
#define BB 64
#define DD 128
#define HH 8
#define HDIM 16
#define FFD 1024
#define NL 6

typedef short bf16x8 __attribute__((ext_vector_type(8)));
typedef float f32x4 __attribute__((ext_vector_type(4)));

__device__ inline short f2bf(float x) {
  union { float f; uint32_t u; } v; v.f = x;
  uint32_t r = v.u + 0x7FFF + ((v.u >> 16) & 1);
  return (short)(r >> 16);
}
__device__ inline uint32_t pack2(float a, float b) {
  return ((uint32_t)(uint16_t)f2bf(a)) | (((uint32_t)(uint16_t)f2bf(b)) << 16);
}

// ---------------- transpose (S,B,D) -> (B,S,D), writes x0 and h ----------------
__global__ __launch_bounds__(256) void transpose_kernel(const float* __restrict__ src,
                                                        float* __restrict__ x0,
                                                        float* __restrict__ h) {
  int f = blockIdx.x * 256 + threadIdx.x;
  int b = f >> 14;
  int rem = f & 16383;
  int s = rem >> 5;
  int d4 = rem & 31;
  const float4 v = ((const float4*)src)[((size_t)s * BB + b) * 32 + d4];
  ((float4*)x0)[f] = v;
  ((float4*)h)[f] = v;
}

// ---------------- per-row reciprocal norm ----------------
__global__ __launch_bounds__(256) void rownorm_kernel(const float* __restrict__ x,
                                                      float* __restrict__ rn) {
  const int wave = threadIdx.x >> 6;
  const int lane = threadIdx.x & 63;
  const size_t row = (size_t)blockIdx.x * 4 + wave;
  const float2 v = ((const float2*)(x + row * DD))[lane];
  float ss = v.x * v.x + v.y * v.y;
  #pragma unroll
  for (int off = 1; off < 64; off <<= 1) ss += __shfl_xor(ss, off);
  if (lane == 0) rn[row] = rsqrtf(ss);
}

// ---------------- generic tiled GEMM (fp32) ----------------
template <bool RELU>
__global__ __launch_bounds__(256) void gemm_kernel(const float* __restrict__ A,
                                                   const float* __restrict__ Bm,
                                                   const float* __restrict__ bias,
                                                   float* __restrict__ C,
                                                   int M, int N, int K) {
  __shared__ float As[64][33];
  __shared__ float Bs[64][33];
  const int t = threadIdx.x;
  const int m0 = blockIdx.y * 64;
  const int n0 = blockIdx.x * 64;
  const int tx = t & 15, ty = t >> 4;
  const int lr = t >> 3;
  const int lc = (t & 7) * 4;
  float acc[4][4] = {};
  for (int kt = 0; kt < K; kt += 32) {
    float4 a0 = *(const float4*)(A + (size_t)(m0 + lr) * K + kt + lc);
    float4 a1 = *(const float4*)(A + (size_t)(m0 + 32 + lr) * K + kt + lc);
    float4 b0 = *(const float4*)(Bm + (size_t)(n0 + lr) * K + kt + lc);
    float4 b1 = *(const float4*)(Bm + (size_t)(n0 + 32 + lr) * K + kt + lc);
    __syncthreads();
    As[lr][lc] = a0.x; As[lr][lc+1] = a0.y; As[lr][lc+2] = a0.z; As[lr][lc+3] = a0.w;
    As[32+lr][lc] = a1.x; As[32+lr][lc+1] = a1.y; As[32+lr][lc+2] = a1.z; As[32+lr][lc+3] = a1.w;
    Bs[lr][lc] = b0.x; Bs[lr][lc+1] = b0.y; Bs[lr][lc+2] = b0.z; Bs[lr][lc+3] = b0.w;
    Bs[32+lr][lc] = b1.x; Bs[32+lr][lc+1] = b1.y; Bs[32+lr][lc+2] = b1.z; Bs[32+lr][lc+3] = b1.w;
    __syncthreads();
    #pragma unroll 8
    for (int kk = 0; kk < 32; ++kk) {
      float a4[4], b4[4];
      #pragma unroll
      for (int i = 0; i < 4; ++i) a4[i] = As[ty * 4 + i][kk];
      #pragma unroll
      for (int j = 0; j < 4; ++j) b4[j] = Bs[tx * 4 + j][kk];
      #pragma unroll
      for (int i = 0; i < 4; ++i)
        #pragma unroll
        for (int j = 0; j < 4; ++j) acc[i][j] = fmaf(a4[i], b4[j], acc[i][j]);
    }
  }
  #pragma unroll
  for (int i = 0; i < 4; ++i) {
    const int m = m0 + ty * 4 + i;
    float4 v;
    float* pv = &v.x;
    #pragma unroll
    for (int j = 0; j < 4; ++j) {
      float c = acc[i][j] + bias[n0 + tx * 4 + j];
      if (RELU) c = fmaxf(c, 0.0f);
      pv[j] = c;
    }
    *(float4*)(C + (size_t)m * N + n0 + tx * 4) = v;
  }
}

// ---------------- batched cosine-sim GEMM ----------------
template <int MODE>
__global__ __launch_bounds__(256) void cos_kernel(const float* __restrict__ X,
                                                  const float* __restrict__ rn,
                                                  float* __restrict__ out) {
  const int b = blockIdx.z;
  const float* Xb = X + (size_t)b * SS * DD;
  __shared__ float As[64][33];
  __shared__ float Bs[64][33];
  const int t = threadIdx.x;
  const int i0 = blockIdx.y * 64;
  const int j0 = blockIdx.x * 64;
  const int tx = t & 15, ty = t >> 4;
  const int lr = t >> 3;
  const int lc = (t & 7) * 4;
  float acc[4][4] = {};
  for (int kt = 0; kt < DD; kt += 32) {
    float4 a0 = *(const float4*)(Xb + (size_t)(i0 + lr) * DD + kt + lc);
    float4 a1 = *(const float4*)(Xb + (size_t)(i0 + 32 + lr) * DD + kt + lc);
    float4 b0 = *(const float4*)(Xb + (size_t)(j0 + lr) * DD + kt + lc);
    float4 b1 = *(const float4*)(Xb + (size_t)(j0 + 32 + lr) * DD + kt + lc);
    __syncthreads();
    As[lr][lc] = a0.x; As[lr][lc+1] = a0.y; As[lr][lc+2] = a0.z; As[lr][lc+3] = a0.w;
    As[32+lr][lc] = a1.x; As[32+lr][lc+1] = a1.y; As[32+lr][lc+2] = a1.z; As[32+lr][lc+3] = a1.w;
    Bs[lr][lc] = b0.x; Bs[lr][lc+1] = b0.y; Bs[lr][lc+2] = b0.z; Bs[lr][lc+3] = b0.w;
    Bs[32+lr][lc] = b1.x; Bs[32+lr][lc+1] = b1.y; Bs[32+lr][lc+2] = b1.z; Bs[32+lr][lc+3] = b1.w;
    __syncthreads();
    #pragma unroll 8
    for (int kk = 0; kk < 32; ++kk) {
      float a4[4], b4[4];
      #pragma unroll
      for (int i = 0; i < 4; ++i) a4[i] = As[ty * 4 + i][kk];
      #pragma unroll
      for (int j = 0; j < 4; ++j) b4[j] = Bs[tx * 4 + j][kk];
      #pragma unroll
      for (int i = 0; i < 4; ++i)
        #pragma unroll
        for (int j = 0; j < 4; ++j) acc[i][j] = fmaf(a4[i], b4[j], acc[i][j]);
    }
  }
  float* ob = out + (size_t)b * SS * SS;
  #pragma unroll
  for (int i = 0; i < 4; ++i) {
    const int ii = i0 + ty * 4 + i;
    float ri = 1.0f;
    if (MODE == 0) ri = rn[b * SS + ii];
    #pragma unroll
    for (int j = 0; j < 4; ++j) {
      const int jj = j0 + tx * 4 + j;
      float v = acc[i][j];
      if (MODE == 0) {
        v = fmaxf(v * ri * rn[b * SS + jj], 1e-6f);
        ob[(size_t)ii * SS + jj] = v;
      } else {
        v = fmaxf(v, 1e-6f);
        float prev = ob[(size_t)ii * SS + jj];
        float r2 = 0.5f * (v + prev);
        r2 = fminf(fmaxf(r2, 0.1f), 0.9f);
        ob[(size_t)ii * SS + jj] = r2;
      }
    }
  }
}

// ---------------- MFMA flash attention (bf16), HD=16 ----------------
// Swapped QK^T: S^T = mfma(A=K_tile, B=Q^T) so each lane owns one q (=lane&15)
// and 4 k-scores per MFMA. PV: O^T += mfma(A=V^T, B=P^T).
// K LDS: [512 rows][16 d] bf16, word = row*8 + (w ^ (((row>>2)&1)<<2))
// V LDS: V^T [16 d][512 k] bf16, word = d*256 + (wk ^ ((d&7)<<2))
__global__ __launch_bounds__(512) void attn_mfma_kernel(const float* __restrict__ qkv,
                                                        float* __restrict__ o_out) {
  const int h = blockIdx.x;
  const int b = blockIdx.y;
  const int t = threadIdx.x;
  const int wave = t >> 6;
  const int lane = t & 63;
  const int g = lane >> 4;
  const int p = lane & 15;

  __shared__ uint32_t Ks[512 * 8];   // 16 KB
  __shared__ uint32_t Vs[16 * 256];  // 16 KB

  const float* base = qkv + (size_t)b * SS * 384;

  // ---- stage K (bf16, swizzled): one row per thread ----
  {
    const int row = t;
    const float* kp = base + (size_t)row * 384 + DD + h * HDIM;
    float4 k0 = *(const float4*)(kp + 0);
    float4 k1 = *(const float4*)(kp + 4);
    float4 k2 = *(const float4*)(kp + 8);
    float4 k3 = *(const float4*)(kp + 12);
    uint4 lo, hi;
    lo.x = pack2(k0.x, k0.y); lo.y = pack2(k0.z, k0.w);
    lo.z = pack2(k1.x, k1.y); lo.w = pack2(k1.z, k1.w);
    hi.x = pack2(k2.x, k2.y); hi.y = pack2(k2.z, k2.w);
    hi.z = pack2(k3.x, k3.y); hi.w = pack2(k3.z, k3.w);
    const int blk = ((row >> 2) & 1) << 2;
    *(uint4*)(Ks + row * 8 + blk) = lo;
    *(uint4*)(Ks + row * 8 + (blk ^ 4)) = hi;
  }
  // ---- stage V^T (bf16, swizzled): one k-row per thread, scattered b16 ----
  {
    const int k = t;
    const float* vp = base + (size_t)k * 384 + 2 * DD + h * HDIM;
    float4 v0 = *(const float4*)(vp + 0);
    float4 v1 = *(const float4*)(vp + 4);
    float4 v2 = *(const float4*)(vp + 8);
    float4 v3 = *(const float4*)(vp + 12);
    float arr[16] = {v0.x, v0.y, v0.z, v0.w, v1.x, v1.y, v1.z, v1.w,
                     v2.x, v2.y, v2.z, v2.w, v3.x, v3.y, v3.z, v3.w};
    const int wk = k >> 1;
    #pragma unroll
    for (int d = 0; d < 16; ++d) {
      const int word = d * 256 + (wk ^ ((d & 7) << 2));
      ((short*)(Vs + word))[k & 1] = f2bf(arr[d]);
    }
  }
  __syncthreads();

  const bf16x8 zfrag = {0, 0, 0, 0, 0, 0, 0, 0};
  const f32x4 zacc = {0.f, 0.f, 0.f, 0.f};

  // 32 q-tiles of 16 rows; 8 waves -> 4 tiles per wave
  for (int qi = 0; qi < 4; ++qi) {
    const int qt = wave + qi * 8;
    // Q B-frag: lane n=p holds Q[qt*16+p][d=g*8+i]; groups 2,3 are zero (d>=16)
    bf16x8 qf = zfrag;
    if (g < 2) {
      const float* qp = base + (size_t)(qt * 16 + p) * 384 + h * HDIM + g * 8;
      float4 q0 = *(const float4*)qp;
      float4 q1 = *(const float4*)(qp + 4);
      union { bf16x8 v; uint4 w; } qu;
      qu.w.x = pack2(q0.x, q0.y); qu.w.y = pack2(q0.z, q0.w);
      qu.w.z = pack2(q1.x, q1.y); qu.w.w = pack2(q1.z, q1.w);
      qf = qu.v;
    }

    f32x4 o = zacc;
    float m = -1e30f, lsum = 0.0f;

    for (int kv = 0; kv < 16; ++kv) {
      // K A-frags for rows [kv*32, kv*32+16) and [kv*32+16, kv*32+32)
      bf16x8 ka = zfrag, kb = zfrag;
      if (g < 2) {
        int row = kv * 32 + p;
        union { bf16x8 v; uint4 w; } u;
        u.w = *(const uint4*)(Ks + row * 8 + (((g & 1) << 2) ^ (((row >> 2) & 1) << 2)));
        ka = u.v;
        row += 16;
        u.w = *(const uint4*)(Ks + row * 8 + (((g & 1) << 2) ^ (((row >> 2) & 1) << 2)));
        kb = u.v;
      }
      f32x4 s0 = __builtin_amdgcn_mfma_f32_16x16x32_bf16(ka, qf, zacc, 0, 0, 0);
      f32x4 s1 = __builtin_amdgcn_mfma_f32_16x16x32_bf16(kb, qf, zacc, 0, 0, 0);

      // scale and online softmax; lane owns q=p, ks {g*4+r} and {16+g*4+r}
      float sv0[4], sv1[4];
      float tmax = -1e30f;
      #pragma unroll
      for (int r = 0; r < 4; ++r) {
        sv0[r] = s0[r] * 0.25f;
        sv1[r] = s1[r] * 0.25f;
        tmax = fmaxf(tmax, fmaxf(sv0[r], sv1[r]));
      }
      tmax = fmaxf(tmax, __shfl_xor(tmax, 16));
      tmax = fmaxf(tmax, __shfl_xor(tmax, 32));
      const float mn = fmaxf(m, tmax);
      const float scale = __expf(m - mn);
      m = mn;
      float ts = 0.0f;
      #pragma unroll
      for (int r = 0; r < 4; ++r) {
        sv0[r] = __expf(sv0[r] - m);
        sv1[r] = __expf(sv1[r] - m);
        ts += sv0[r] + sv1[r];
      }
      ts += __shfl_xor(ts, 16);
      ts += __shfl_xor(ts, 32);
      lsum = lsum * scale + ts;
      #pragma unroll
      for (int r = 0; r < 4; ++r) o[r] *= scale;

      // pack P to bf16 pairs: c0={4g,4g+1} c1={4g+2,4g+3} c2={16+4g,16+4g+1} c3={16+4g+2,+3}
      uint32_t c0 = pack2(sv0[0], sv0[1]);
      uint32_t c1 = pack2(sv0[2], sv0[3]);
      uint32_t c2 = pack2(sv1[0], sv1[1]);
      uint32_t c3 = pack2(sv1[2], sv1[3]);
      // redistribute to B-frag: lane (g,p) reg j holds pair {g*8+2j, g*8+2j+1}
      const int srcA = (((2 * g) & 3) << 4) | p;
      const int srcB = (((2 * g + 1) & 3) << 4) | p;
      uint32_t a0 = (uint32_t)__shfl((int)c0, srcA);
      uint32_t a2 = (uint32_t)__shfl((int)c2, srcA);
      uint32_t b0 = (uint32_t)__shfl((int)c1, srcA);
      uint32_t b2 = (uint32_t)__shfl((int)c3, srcA);
      uint32_t d0 = (uint32_t)__shfl((int)c0, srcB);
      uint32_t d2 = (uint32_t)__shfl((int)c2, srcB);
      uint32_t e0 = (uint32_t)__shfl((int)c1, srcB);
      uint32_t e2 = (uint32_t)__shfl((int)c3, srcB);
      union { bf16x8 v; uint4 w; } pu;
      pu.w.x = (g < 2) ? a0 : a2;
      pu.w.y = (g < 2) ? b0 : b2;
      pu.w.z = (g < 2) ? d0 : d2;
      pu.w.w = (g < 2) ? e0 : e2;

      // V^T A-frag: lane m=p holds V^T[d=p][k = kv*32+g*8+i]
      union { bf16x8 v; uint4 w; } vu;
      vu.w = *(const uint4*)(Vs + p * 256 + ((kv * 16 + g * 4) ^ ((p & 7) << 2)));

      o = __builtin_amdgcn_mfma_f32_16x16x32_bf16(vu.v, pu.v, o, 0, 0, 0);
    }

    const float inv = 1.0f / lsum;
    float4 w;
    w.x = o[0] * inv; w.y = o[1] * inv; w.z = o[2] * inv; w.w = o[3] * inv;
    *(float4*)(o_out + ((size_t)(b * SS + qt * 16 + p)) * DD + h * HDIM + g * 4) = w;
  }
}

// ---------------- x = LN(x + r) rowwise ----------------
__global__ __launch_bounds__(256) void add_ln_kernel(float* __restrict__ x,
                                                     const float* __restrict__ r,
                                                     const float* __restrict__ g,
                                                     const float* __restrict__ bb) {
  const int wave = threadIdx.x >> 6;
  const int lane = threadIdx.x & 63;
  const size_t row = (size_t)blockIdx.x * 4 + wave;
  float2 xv = ((const float2*)(x + row * DD))[lane];
  float2 rv = ((const float2*)(r + row * DD))[lane];
  const float a = xv.x + rv.x, c = xv.y + rv.y;
  float sum = a + c;
  #pragma unroll
  for (int off = 1; off < 64; off <<= 1) sum += __shfl_xor(sum, off);
  const float mu = sum * (1.0f / 128.0f);
  const float da = a - mu, dc = c - mu;
  float v = da * da + dc * dc;
  #pragma unroll
  for (int off = 1; off < 64; off <<= 1) v += __shfl_xor(v, off);
  const float rs = rsqrtf(v * (1.0f / 128.0f) + 1e-5f);
  const float2 gv = ((const float2*)g)[lane];
  const float2 bv = ((const float2*)bb)[lane];
  float2 ov;
  ov.x = da * rs * gv.x + bv.x;
  ov.y = dc * rs * gv.y + bv.y;
  ((float2*)(x + row * DD))[lane] = ov;
}

// ---------------- y = normalize(sigmoid(h) * x0) rowwise ----------------
__global__ __launch_bounds__(256) void mask_norm_kernel(const float* __restrict__ h,
                                                        const float* __restrict__ x0,
                                                        float* __restrict__ y) {
  const int wave = threadIdx.x >> 6;
  const int lane = threadIdx.x & 63;
  const size_t row = (size_t)blockIdx.x * 4 + wave;
  const float2 hv = ((const float2*)(h + row * DD))[lane];
  const float2 xv = ((const float2*)(x0 + row * DD))[lane];
  const float a = xv.x / (1.0f + __expf(-hv.x));
  const float c = xv.y / (1.0f + __expf(-hv.y));
  float ss = a * a + c * c;
  #pragma unroll
  for (int off = 1; off < 64; off <<= 1) ss += __shfl_xor(ss, off);
  const float inv = 1.0f / fmaxf(sqrtf(ss), 1e-12f);
  float2 ov; ov.x = a * inv; ov.y = c * inv;
  ((float2*)(y + row * DD))[lane] = ov;
}

extern "C" void kernel_launch(void* const* d_in, const int* in_sizes, int n_in,
                              void* d_out, int out_size, void* d_ws, size_t ws_size,
                              hipStream_t stream) {
  const float* src  = (const float*)d_in[0];
  const float* Wqkv = (const float*)d_in[1];
  const float* bqkv = (const float*)d_in[2];
  const float* Wo   = (const float*)d_in[3];
  const float* bo   = (const float*)d_in[4];
  const float* ln1g = (const float*)d_in[5];
  const float* ln1b = (const float*)d_in[6];
  const float* W1   = (const float*)d_in[7];
  const float* b1   = (const float*)d_in[8];
  const float* W2   = (const float*)d_in[9];
  const float* b2   = (const float*)d_in[10];
  const float* ln2g = (const float*)d_in[11];
  const float* ln2b = (const float*)d_in[12];
  float* out = (float*)d_out;

  float* ws = (float*)d_ws;
  const size_t XSZ = (size_t)BB * SS * DD;
  const size_t BIGSZ = (size_t)BB * SS * FFD;
  float* x0   = ws;
  float* h    = ws + XSZ;
  float* big  = ws + 2 * XSZ;
  float* smal = ws + 2 * XSZ + BIGSZ;
  float* rn   = ws + 3 * XSZ + BIGSZ;

  const dim3 blk(256);
  const int ROWS = BB * SS;

  transpose_kernel<<<4096, blk, 0, stream>>>(src, x0, h);
  rownorm_kernel<<<ROWS / 4, blk, 0, stream>>>(x0, rn);
  cos_kernel<0><<<dim3(8, 8, BB), blk, 0, stream>>>(x0, rn, out);

  for (int l = 0; l < NL; ++l) {
    gemm_kernel<false><<<dim3(6, ROWS / 64), blk, 0, stream>>>(
        h, Wqkv + (size_t)l * 384 * DD, bqkv + l * 384, big, ROWS, 384, DD);
    attn_mfma_kernel<<<dim3(HH, BB), dim3(512), 0, stream>>>(big, smal);
    gemm_kernel<false><<<dim3(2, ROWS / 64), blk, 0, stream>>>(
        smal, Wo + (size_t)l * DD * DD, bo + l * DD, big, ROWS, DD, DD);
    add_ln_kernel<<<ROWS / 4, blk, 0, stream>>>(h, big, ln1g + l * DD, ln1b + l * DD);
    gemm_kernel<true><<<dim3(16, ROWS / 64), blk, 0, stream>>>(
        h, W1 + (size_t)l * FFD * DD, b1 + l * FFD, big, ROWS, FFD, DD);
    gemm_kernel<false><<<dim3(2, ROWS / 64), blk, 0, stream>>>(
        big, W2 + (size_t)l * DD * FFD, b2 + l * DD, smal, ROWS, DD, FFD);
    add_ln_kernel<<<ROWS / 4, blk, 0, stream>>>(h, smal, ln2g + l * DD, ln2b + l * DD);
  }

  mask_norm_kernel<<<ROWS / 4, blk, 0, stream>>>(h, x0, smal);
  cos_kernel<1><<<dim3(8, 8, BB), blk, 0, stream>>>(smal, nullptr, out);
}

// Round 3
// 1189.649 us; speedup vs baseline: 4.2293x; 2.6661x over previous
//
#include <hip/hip_runtime.h>
#include <cstdint>
#include <cstddef>

#define SS 512
#define BB 64
#define DD 128
#define HH 8
#define HDIM 16
#define FFD 1024
#define NL 6

typedef short bf16x8 __attribute__((ext_vector_type(8)));
typedef float f32x4 __attribute__((ext_vector_type(4)));

__device__ inline short f2bf(float x) {
  union { float f; uint32_t u; } v; v.f = x;
  uint32_t r = v.u + 0x7FFF + ((v.u >> 16) & 1);
  return (short)(r >> 16);
}
__device__ inline uint32_t pack2(float a, float b) {
  return ((uint32_t)(uint16_t)f2bf(a)) | (((uint32_t)(uint16_t)f2bf(b)) << 16);
}

// ---------------- fp32 -> bf16 convert (weights) ----------------
__global__ __launch_bounds__(256) void cvt_kernel(const float* __restrict__ s,
                                                  short* __restrict__ d, int n2) {
  int i = blockIdx.x * 256 + threadIdx.x;
  if (i < n2) {
    float2 v = ((const float2*)s)[i];
    ((uint32_t*)d)[i] = pack2(v.x, v.y);
  }
}

// ---------------- transpose (S,B,D) -> (B,S,D), writes x0 and h ----------------
__global__ __launch_bounds__(256) void transpose_kernel(const float* __restrict__ src,
                                                        float* __restrict__ x0,
                                                        float* __restrict__ h) {
  int f = blockIdx.x * 256 + threadIdx.x;
  int b = f >> 14;
  int rem = f & 16383;
  int s = rem >> 5;
  int d4 = rem & 31;
  const float4 v = ((const float4*)src)[((size_t)s * BB + b) * 32 + d4];
  ((float4*)x0)[f] = v;
  ((float4*)h)[f] = v;
}

// ---------------- per-row normalize -> bf16 ----------------
__global__ __launch_bounds__(256) void rownorm_kernel(const float* __restrict__ x,
                                                      short* __restrict__ xn) {
  const int wave = threadIdx.x >> 6;
  const int lane = threadIdx.x & 63;
  const size_t row = (size_t)blockIdx.x * 4 + wave;
  const float2 v = ((const float2*)(x + row * DD))[lane];
  float ss = v.x * v.x + v.y * v.y;
  #pragma unroll
  for (int off = 1; off < 64; off <<= 1) ss += __shfl_xor(ss, off);
  const float r = rsqrtf(ss);
  ((uint32_t*)xn)[row * 64 + lane] = pack2(v.x * r, v.y * r);
}

// ---------------- MFMA GEMM: C[m,n] = epilogue(sum_k A[m,k]*B[n,k]) ----------------
// MODE 0: + bias[n], optional ReLU.  MODE 1: max(.,1e-6).  MODE 2: clip(0.5*(max(.,1e-6)+prev),0.1,0.9)
// Tile 128x128, BK=64, 4 waves (2x2), mfma_f32_16x16x32_bf16.
// mfma(A=Wrow-frag, B=Xrow-frag): D[n][m]; C-layout: m=lane&15, n=(lane>>4)*4+reg.
template <int MODE, bool ABF, bool CBF, bool RELU>
__global__ __launch_bounds__(256) void mgemm(const void* __restrict__ Ap,
                                             const short* __restrict__ Bw,
                                             const float* __restrict__ bias,
                                             void* __restrict__ Cp,
                                             int M, int N, int K,
                                             long sA, long sB, long sC) {
  __shared__ uint32_t Xs[128 * 32];  // 128 rows x 64 bf16, 16B-slot XOR swizzle
  __shared__ uint32_t Wls[128 * 32];
  const int t = threadIdx.x;
  const int wave = t >> 6, lane = t & 63;
  const int g = lane >> 4, p = lane & 15;
  const int wr = wave >> 1, wc = wave & 1;
  const int m0 = blockIdx.y * 128, n0 = blockIdx.x * 128;
  const int z = blockIdx.z;
  const float* Af = (const float*)Ap + (ABF ? (size_t)0 : (size_t)z * sA);
  const short* Ab = (const short*)Ap + (ABF ? (size_t)z * sA : (size_t)0);
  const short* Bb = Bw + (size_t)z * sB;
  float* Cf = (float*)Cp + (CBF ? (size_t)0 : (size_t)z * sC);
  short* Cb = (short*)Cp + (CBF ? (size_t)z * sC : (size_t)0);

  f32x4 acc[4][4];
  #pragma unroll
  for (int i = 0; i < 4; ++i)
    #pragma unroll
    for (int j = 0; j < 4; ++j) acc[i][j] = (f32x4){0.f, 0.f, 0.f, 0.f};

  for (int kt = 0; kt < K; kt += 64) {
    __syncthreads();
    #pragma unroll
    for (int i = 0; i < 4; ++i) {
      const int idx = t + i * 256;
      const int row = idx >> 3, kc = idx & 7;
      uint4 w;
      if (ABF) {
        w = *(const uint4*)(Ab + (size_t)(m0 + row) * K + kt + kc * 8);
      } else {
        const float* pp = Af + (size_t)(m0 + row) * K + kt + kc * 8;
        const float4 f0 = *(const float4*)pp;
        const float4 f1 = *(const float4*)(pp + 4);
        w.x = pack2(f0.x, f0.y); w.y = pack2(f0.z, f0.w);
        w.z = pack2(f1.x, f1.y); w.w = pack2(f1.z, f1.w);
      }
      *(uint4*)(Xs + row * 32 + ((kc ^ (row & 7)) << 2)) = w;
      const uint4 u = *(const uint4*)(Bb + (size_t)(n0 + row) * K + kt + kc * 8);
      *(uint4*)(Wls + row * 32 + ((kc ^ (row & 7)) << 2)) = u;
    }
    __syncthreads();
    #pragma unroll
    for (int kc32 = 0; kc32 < 2; ++kc32) {
      bf16x8 xf[4], wf[4];
      #pragma unroll
      for (int mi = 0; mi < 4; ++mi) {
        const int row = wr * 64 + mi * 16 + p;
        union { bf16x8 v; uint4 w; } u;
        u.w = *(const uint4*)(Xs + row * 32 + (((kc32 * 4 + g) ^ (row & 7)) << 2));
        xf[mi] = u.v;
      }
      #pragma unroll
      for (int ni = 0; ni < 4; ++ni) {
        const int row = wc * 64 + ni * 16 + p;
        union { bf16x8 v; uint4 w; } u;
        u.w = *(const uint4*)(Wls + row * 32 + (((kc32 * 4 + g) ^ (row & 7)) << 2));
        wf[ni] = u.v;
      }
      #pragma unroll
      for (int mi = 0; mi < 4; ++mi)
        #pragma unroll
        for (int ni = 0; ni < 4; ++ni)
          acc[mi][ni] = __builtin_amdgcn_mfma_f32_16x16x32_bf16(wf[ni], xf[mi], acc[mi][ni], 0, 0, 0);
    }
  }

  #pragma unroll
  for (int mi = 0; mi < 4; ++mi) {
    const int m = m0 + wr * 64 + mi * 16 + p;
    #pragma unroll
    for (int ni = 0; ni < 4; ++ni) {
      const int nb = n0 + wc * 64 + ni * 16 + g * 4;
      float c[4];
      if (MODE == 0) {
        const float4 bv = *(const float4*)(bias + nb);
        const float bp[4] = {bv.x, bv.y, bv.z, bv.w};
        #pragma unroll
        for (int r = 0; r < 4; ++r) {
          c[r] = acc[mi][ni][r] + bp[r];
          if (RELU) c[r] = fmaxf(c[r], 0.0f);
        }
      } else if (MODE == 1) {
        #pragma unroll
        for (int r = 0; r < 4; ++r) c[r] = fmaxf(acc[mi][ni][r], 1e-6f);
      } else {
        const float4 pv = *(const float4*)(Cf + (size_t)m * N + nb);
        const float pp[4] = {pv.x, pv.y, pv.z, pv.w};
        #pragma unroll
        for (int r = 0; r < 4; ++r) {
          float v = fmaxf(acc[mi][ni][r], 1e-6f);
          c[r] = fminf(fmaxf(0.5f * (v + pp[r]), 0.1f), 0.9f);
        }
      }
      if (CBF) {
        uint2 w;
        w.x = pack2(c[0], c[1]);
        w.y = pack2(c[2], c[3]);
        *(uint2*)(Cb + (size_t)m * N + nb) = w;
      } else {
        float4 w;
        w.x = c[0]; w.y = c[1]; w.z = c[2]; w.w = c[3];
        *(float4*)(Cf + (size_t)m * N + nb) = w;
      }
    }
  }
}

// ---------------- MFMA flash attention (bf16 in/out), HD=16 ----------------
__global__ __launch_bounds__(512) void attn_mfma_kernel(const short* __restrict__ qkv,
                                                        short* __restrict__ o_out) {
  const int h = blockIdx.x;
  const int b = blockIdx.y;
  const int t = threadIdx.x;
  const int wave = t >> 6;
  const int lane = t & 63;
  const int g = lane >> 4;
  const int p = lane & 15;

  __shared__ uint32_t Ks[512 * 8];   // 16 KB
  __shared__ uint32_t Vs[16 * 256];  // 16 KB

  const short* base = qkv + (size_t)b * SS * 384;

  // ---- stage K (swizzled): one row per thread ----
  {
    const int row = t;
    const short* kp = base + (size_t)row * 384 + DD + h * HDIM;
    const uint4 lo = *(const uint4*)kp;
    const uint4 hi = *(const uint4*)(kp + 8);
    const int blk = ((row >> 2) & 1) << 2;
    *(uint4*)(Ks + row * 8 + blk) = lo;
    *(uint4*)(Ks + row * 8 + (blk ^ 4)) = hi;
  }
  // ---- stage V^T (swizzled): one k-row per thread, scattered b16 ----
  {
    const int k = t;
    const short* vp = base + (size_t)k * 384 + 2 * DD + h * HDIM;
    union { uint4 u[2]; short s[16]; } vv;
    vv.u[0] = *(const uint4*)vp;
    vv.u[1] = *(const uint4*)(vp + 8);
    const int wk = k >> 1;
    #pragma unroll
    for (int d = 0; d < 16; ++d) {
      const int word = d * 256 + (wk ^ ((d & 7) << 2));
      ((short*)(Vs + word))[k & 1] = vv.s[d];
    }
  }
  __syncthreads();

  const bf16x8 zfrag = {0, 0, 0, 0, 0, 0, 0, 0};
  const f32x4 zacc = {0.f, 0.f, 0.f, 0.f};

  for (int qi = 0; qi < 4; ++qi) {
    const int qt = wave + qi * 8;
    bf16x8 qf = zfrag;
    if (g < 2) {
      const short* qp = base + (size_t)(qt * 16 + p) * 384 + h * HDIM + g * 8;
      union { bf16x8 v; uint4 w; } qu;
      qu.w = *(const uint4*)qp;
      qf = qu.v;
    }

    f32x4 o = zacc;
    float m = -1e30f, lsum = 0.0f;

    for (int kv = 0; kv < 16; ++kv) {
      bf16x8 ka = zfrag, kb = zfrag;
      if (g < 2) {
        int row = kv * 32 + p;
        union { bf16x8 v; uint4 w; } u;
        u.w = *(const uint4*)(Ks + row * 8 + (((g & 1) << 2) ^ (((row >> 2) & 1) << 2)));
        ka = u.v;
        row += 16;
        u.w = *(const uint4*)(Ks + row * 8 + (((g & 1) << 2) ^ (((row >> 2) & 1) << 2)));
        kb = u.v;
      }
      f32x4 s0 = __builtin_amdgcn_mfma_f32_16x16x32_bf16(ka, qf, zacc, 0, 0, 0);
      f32x4 s1 = __builtin_amdgcn_mfma_f32_16x16x32_bf16(kb, qf, zacc, 0, 0, 0);

      float sv0[4], sv1[4];
      float tmax = -1e30f;
      #pragma unroll
      for (int r = 0; r < 4; ++r) {
        sv0[r] = s0[r] * 0.25f;
        sv1[r] = s1[r] * 0.25f;
        tmax = fmaxf(tmax, fmaxf(sv0[r], sv1[r]));
      }
      tmax = fmaxf(tmax, __shfl_xor(tmax, 16));
      tmax = fmaxf(tmax, __shfl_xor(tmax, 32));
      const float mn = fmaxf(m, tmax);
      const float scale = __expf(m - mn);
      m = mn;
      float ts = 0.0f;
      #pragma unroll
      for (int r = 0; r < 4; ++r) {
        sv0[r] = __expf(sv0[r] - m);
        sv1[r] = __expf(sv1[r] - m);
        ts += sv0[r] + sv1[r];
      }
      ts += __shfl_xor(ts, 16);
      ts += __shfl_xor(ts, 32);
      lsum = lsum * scale + ts;
      #pragma unroll
      for (int r = 0; r < 4; ++r) o[r] *= scale;

      uint32_t c0 = pack2(sv0[0], sv0[1]);
      uint32_t c1 = pack2(sv0[2], sv0[3]);
      uint32_t c2 = pack2(sv1[0], sv1[1]);
      uint32_t c3 = pack2(sv1[2], sv1[3]);
      const int srcA = (((2 * g) & 3) << 4) | p;
      const int srcB = (((2 * g + 1) & 3) << 4) | p;
      uint32_t a0 = (uint32_t)__shfl((int)c0, srcA);
      uint32_t a2 = (uint32_t)__shfl((int)c2, srcA);
      uint32_t b0 = (uint32_t)__shfl((int)c1, srcA);
      uint32_t b2 = (uint32_t)__shfl((int)c3, srcA);
      uint32_t d0 = (uint32_t)__shfl((int)c0, srcB);
      uint32_t d2 = (uint32_t)__shfl((int)c2, srcB);
      uint32_t e0 = (uint32_t)__shfl((int)c1, srcB);
      uint32_t e2 = (uint32_t)__shfl((int)c3, srcB);
      union { bf16x8 v; uint4 w; } pu;
      pu.w.x = (g < 2) ? a0 : a2;
      pu.w.y = (g < 2) ? b0 : b2;
      pu.w.z = (g < 2) ? d0 : d2;
      pu.w.w = (g < 2) ? e0 : e2;

      union { bf16x8 v; uint4 w; } vu;
      vu.w = *(const uint4*)(Vs + p * 256 + ((kv * 16 + g * 4) ^ ((p & 7) << 2)));

      o = __builtin_amdgcn_mfma_f32_16x16x32_bf16(vu.v, pu.v, o, 0, 0, 0);
    }

    const float inv = 1.0f / lsum;
    uint2 w;
    w.x = pack2(o[0] * inv, o[1] * inv);
    w.y = pack2(o[2] * inv, o[3] * inv);
    *(uint2*)(o_out + ((size_t)(b * SS + qt * 16 + p)) * DD + h * HDIM + g * 4) = w;
  }
}

// ---------------- x = LN(x + r) rowwise (fp32) ----------------
__global__ __launch_bounds__(256) void add_ln_kernel(float* __restrict__ x,
                                                     const float* __restrict__ r,
                                                     const float* __restrict__ g,
                                                     const float* __restrict__ bb) {
  const int wave = threadIdx.x >> 6;
  const int lane = threadIdx.x & 63;
  const size_t row = (size_t)blockIdx.x * 4 + wave;
  float2 xv = ((const float2*)(x + row * DD))[lane];
  float2 rv = ((const float2*)(r + row * DD))[lane];
  const float a = xv.x + rv.x, c = xv.y + rv.y;
  float sum = a + c;
  #pragma unroll
  for (int off = 1; off < 64; off <<= 1) sum += __shfl_xor(sum, off);
  const float mu = sum * (1.0f / 128.0f);
  const float da = a - mu, dc = c - mu;
  float v = da * da + dc * dc;
  #pragma unroll
  for (int off = 1; off < 64; off <<= 1) v += __shfl_xor(v, off);
  const float rs = rsqrtf(v * (1.0f / 128.0f) + 1e-5f);
  const float2 gv = ((const float2*)g)[lane];
  const float2 bv = ((const float2*)bb)[lane];
  float2 ov;
  ov.x = da * rs * gv.x + bv.x;
  ov.y = dc * rs * gv.y + bv.y;
  ((float2*)(x + row * DD))[lane] = ov;
}

// ---------------- yn = normalize(sigmoid(h) * x0) rowwise -> bf16 ----------------
__global__ __launch_bounds__(256) void mask_norm_kernel(const float* __restrict__ h,
                                                        const float* __restrict__ x0,
                                                        short* __restrict__ yn) {
  const int wave = threadIdx.x >> 6;
  const int lane = threadIdx.x & 63;
  const size_t row = (size_t)blockIdx.x * 4 + wave;
  const float2 hv = ((const float2*)(h + row * DD))[lane];
  const float2 xv = ((const float2*)(x0 + row * DD))[lane];
  const float a = xv.x / (1.0f + __expf(-hv.x));
  const float c = xv.y / (1.0f + __expf(-hv.y));
  float ss = a * a + c * c;
  #pragma unroll
  for (int off = 1; off < 64; off <<= 1) ss += __shfl_xor(ss, off);
  const float inv = 1.0f / fmaxf(sqrtf(ss), 1e-12f);
  ((uint32_t*)yn)[row * 64 + lane] = pack2(a * inv, c * inv);
}

extern "C" void kernel_launch(void* const* d_in, const int* in_sizes, int n_in,
                              void* d_out, int out_size, void* d_ws, size_t ws_size,
                              hipStream_t stream) {
  const float* src  = (const float*)d_in[0];
  const float* Wqkv = (const float*)d_in[1];
  const float* bqkv = (const float*)d_in[2];
  const float* Wo   = (const float*)d_in[3];
  const float* bo   = (const float*)d_in[4];
  const float* ln1g = (const float*)d_in[5];
  const float* ln1b = (const float*)d_in[6];
  const float* W1   = (const float*)d_in[7];
  const float* b1   = (const float*)d_in[8];
  const float* W2   = (const float*)d_in[9];
  const float* b2   = (const float*)d_in[10];
  const float* ln2g = (const float*)d_in[11];
  const float* ln2b = (const float*)d_in[12];
  float* out = (float*)d_out;

  char* W = (char*)d_ws;
  float* x0   = (float*)(W);                       // 16 MB
  float* h    = (float*)(W + 16777216);            // 16 MB
  float* proj = (float*)(W + 33554432);            // 16 MB
  short* qkv  = (short*)(W + 50331648);            // 24 MB (bf16)
  short* ff1  = (short*)(W + 75497472);            // 64 MB (bf16)
  short* att  = (short*)(W + 142606336);           // 8 MB (bf16)
  short* xn   = (short*)(W + 150994944);           // 8 MB (bf16)
  short* yn   = (short*)(W + 159383552);           // 8 MB (bf16)
  short* wqB  = (short*)(W + 167772160);           // 6*384*128
  short* woB  = wqB + (size_t)NL * 384 * DD;
  short* w1B  = woB + (size_t)NL * DD * DD;
  short* w2B  = w1B + (size_t)NL * FFD * DD;

  const dim3 blk(256);
  const int ROWS = BB * SS;  // 32768

  // weights -> bf16
  cvt_kernel<<<(NL * 384 * DD / 2 + 255) / 256, blk, 0, stream>>>(Wqkv, wqB, NL * 384 * DD / 2);
  cvt_kernel<<<(NL * DD * DD / 2 + 255) / 256, blk, 0, stream>>>(Wo, woB, NL * DD * DD / 2);
  cvt_kernel<<<(NL * FFD * DD / 2 + 255) / 256, blk, 0, stream>>>(W1, w1B, NL * FFD * DD / 2);
  cvt_kernel<<<(NL * DD * FFD / 2 + 255) / 256, blk, 0, stream>>>(W2, w2B, NL * DD * FFD / 2);

  transpose_kernel<<<4096, blk, 0, stream>>>(src, x0, h);
  rownorm_kernel<<<ROWS / 4, blk, 0, stream>>>(x0, xn);
  mgemm<1, true, false, false><<<dim3(4, 4, BB), blk, 0, stream>>>(
      xn, xn, nullptr, out, SS, SS, DD, (long)SS * DD, (long)SS * DD, (long)SS * SS);

  for (int l = 0; l < NL; ++l) {
    mgemm<0, false, true, false><<<dim3(3, ROWS / 128, 1), blk, 0, stream>>>(
        h, wqB + (size_t)l * 384 * DD, bqkv + l * 384, qkv, ROWS, 384, DD, 0, 0, 0);
    attn_mfma_kernel<<<dim3(HH, BB), dim3(512), 0, stream>>>(qkv, att);
    mgemm<0, true, false, false><<<dim3(1, ROWS / 128, 1), blk, 0, stream>>>(
        att, woB + (size_t)l * DD * DD, bo + l * DD, proj, ROWS, DD, DD, 0, 0, 0);
    add_ln_kernel<<<ROWS / 4, blk, 0, stream>>>(h, proj, ln1g + l * DD, ln1b + l * DD);
    mgemm<0, false, true, true><<<dim3(8, ROWS / 128, 1), blk, 0, stream>>>(
        h, w1B + (size_t)l * FFD * DD, b1 + l * FFD, ff1, ROWS, FFD, DD, 0, 0, 0);
    mgemm<0, true, false, false><<<dim3(1, ROWS / 128, 1), blk, 0, stream>>>(
        ff1, w2B + (size_t)l * DD * FFD, b2 + l * DD, proj, ROWS, DD, FFD, 0, 0, 0);
    add_ln_kernel<<<ROWS / 4, blk, 0, stream>>>(h, proj, ln2g + l * DD, ln2b + l * DD);
  }

  mask_norm_kernel<<<ROWS / 4, blk, 0, stream>>>(h, x0, yn);
  mgemm<2, true, false, false><<<dim3(4, 4, BB), blk, 0, stream>>>(
      yn, yn, nullptr, out, SS, SS, DD, (long)SS * DD, (long)SS * DD, (long)SS * SS);
}

// Round 4
// 982.664 us; speedup vs baseline: 5.1201x; 1.2106x over previous
//
#include <hip/hip_runtime.h>
#include <cstdint>
#include <cstddef>

#define SS 512
#define BB 64
#define DD 128
#define HH 8
#define HDIM 16
#define FFD 1024
#define NL 6

typedef short bf16x8 __attribute__((ext_vector_type(8)));
typedef float f32x4 __attribute__((ext_vector_type(4)));

// hardware packed f32->bf16 (RNE), low16 = a, high16 = b
__device__ inline uint32_t pack2(float a, float b) {
  uint32_t r;
  asm("v_cvt_pk_bf16_f32 %0, %1, %2" : "=v"(r) : "v"(a), "v"(b));
  return r;
}

// ---------------- fp32 -> bf16 convert (weights) ----------------
__global__ __launch_bounds__(256) void cvt_kernel(const float* __restrict__ s,
                                                  short* __restrict__ d, int n2) {
  int i = blockIdx.x * 256 + threadIdx.x;
  if (i < n2) {
    float2 v = ((const float2*)s)[i];
    ((uint32_t*)d)[i] = pack2(v.x, v.y);
  }
}

// qkv weights: scale Q rows (n<128) by 0.25 = 1/sqrt(HD)
__global__ __launch_bounds__(256) void cvt_qkv_kernel(const float* __restrict__ s,
                                                      short* __restrict__ d) {
  int i = blockIdx.x * 256 + threadIdx.x;
  if (i < NL * 384 * 64) {
    const int within = i % (384 * 64);
    const float sc = (within < 128 * 64) ? 0.25f : 1.0f;
    float2 v = ((const float2*)s)[i];
    ((uint32_t*)d)[i] = pack2(v.x * sc, v.y * sc);
  }
}

__global__ __launch_bounds__(256) void scale_bq_kernel(const float* __restrict__ s,
                                                       float* __restrict__ d) {
  int i = blockIdx.x * 256 + threadIdx.x;
  if (i < NL * 384) {
    const float sc = ((i % 384) < 128) ? 0.25f : 1.0f;
    d[i] = s[i] * sc;
  }
}

// ---------------- transpose (S,B,D) -> (B,S,D): x0 fp32, h fp32, hb bf16 ----------------
__global__ __launch_bounds__(256) void transpose_kernel(const float* __restrict__ src,
                                                        float* __restrict__ x0,
                                                        float* __restrict__ h,
                                                        short* __restrict__ hb) {
  int f = blockIdx.x * 256 + threadIdx.x;
  int b = f >> 14;
  int rem = f & 16383;
  int s = rem >> 5;
  int d4 = rem & 31;
  const float4 v = ((const float4*)src)[((size_t)s * BB + b) * 32 + d4];
  ((float4*)x0)[f] = v;
  ((float4*)h)[f] = v;
  uint2 pb;
  pb.x = pack2(v.x, v.y);
  pb.y = pack2(v.z, v.w);
  ((uint2*)hb)[f] = pb;
}

// ---------------- per-row normalize -> bf16 ----------------
__global__ __launch_bounds__(256) void rownorm_kernel(const float* __restrict__ x,
                                                      short* __restrict__ xn) {
  const int wave = threadIdx.x >> 6;
  const int lane = threadIdx.x & 63;
  const size_t row = (size_t)blockIdx.x * 4 + wave;
  const float2 v = ((const float2*)(x + row * DD))[lane];
  float ss = v.x * v.x + v.y * v.y;
  #pragma unroll
  for (int off = 1; off < 64; off <<= 1) ss += __shfl_xor(ss, off);
  const float r = rsqrtf(ss);
  ((uint32_t*)xn)[row * 64 + lane] = pack2(v.x * r, v.y * r);
}

// ---------------- MFMA GEMM: C[m,n] = epilogue(sum_k A[m,k]*B[n,k]) ----------------
// MODE 0: + bias[n], optional ReLU.  MODE 1: max(.,1e-6).  MODE 2: clip(0.5*(max(.,1e-6)+prev),0.1,0.9)
template <int MODE, bool CBF, bool RELU>
__global__ __launch_bounds__(256) void mgemm(const short* __restrict__ Ab0,
                                             const short* __restrict__ Bw,
                                             const float* __restrict__ bias,
                                             void* __restrict__ Cp,
                                             int M, int N, int K,
                                             long sA, long sB, long sC) {
  __shared__ uint32_t Xs[128 * 32];
  __shared__ uint32_t Wls[128 * 32];
  const int t = threadIdx.x;
  const int wave = t >> 6, lane = t & 63;
  const int g = lane >> 4, p = lane & 15;
  const int wr = wave >> 1, wc = wave & 1;
  const int m0 = blockIdx.y * 128, n0 = blockIdx.x * 128;
  const int z = blockIdx.z;
  const short* Ab = Ab0 + (size_t)z * sA;
  const short* Bb = Bw + (size_t)z * sB;
  float* Cf = (float*)Cp + (CBF ? (size_t)0 : (size_t)z * sC);
  short* Cb = (short*)Cp;

  f32x4 acc[4][4];
  #pragma unroll
  for (int i = 0; i < 4; ++i)
    #pragma unroll
    for (int j = 0; j < 4; ++j) acc[i][j] = (f32x4){0.f, 0.f, 0.f, 0.f};

  for (int kt = 0; kt < K; kt += 64) {
    __syncthreads();
    #pragma unroll
    for (int i = 0; i < 4; ++i) {
      const int idx = t + i * 256;
      const int row = idx >> 3, kc = idx & 7;
      const uint4 w = *(const uint4*)(Ab + (size_t)(m0 + row) * K + kt + kc * 8);
      *(uint4*)(Xs + row * 32 + ((kc ^ (row & 7)) << 2)) = w;
      const uint4 u = *(const uint4*)(Bb + (size_t)(n0 + row) * K + kt + kc * 8);
      *(uint4*)(Wls + row * 32 + ((kc ^ (row & 7)) << 2)) = u;
    }
    __syncthreads();
    #pragma unroll
    for (int kc32 = 0; kc32 < 2; ++kc32) {
      bf16x8 xf[4], wf[4];
      #pragma unroll
      for (int mi = 0; mi < 4; ++mi) {
        const int row = wr * 64 + mi * 16 + p;
        union { bf16x8 v; uint4 w; } u;
        u.w = *(const uint4*)(Xs + row * 32 + (((kc32 * 4 + g) ^ (row & 7)) << 2));
        xf[mi] = u.v;
      }
      #pragma unroll
      for (int ni = 0; ni < 4; ++ni) {
        const int row = wc * 64 + ni * 16 + p;
        union { bf16x8 v; uint4 w; } u;
        u.w = *(const uint4*)(Wls + row * 32 + (((kc32 * 4 + g) ^ (row & 7)) << 2));
        wf[ni] = u.v;
      }
      #pragma unroll
      for (int mi = 0; mi < 4; ++mi)
        #pragma unroll
        for (int ni = 0; ni < 4; ++ni)
          acc[mi][ni] = __builtin_amdgcn_mfma_f32_16x16x32_bf16(wf[ni], xf[mi], acc[mi][ni], 0, 0, 0);
    }
  }

  #pragma unroll
  for (int mi = 0; mi < 4; ++mi) {
    const int m = m0 + wr * 64 + mi * 16 + p;
    #pragma unroll
    for (int ni = 0; ni < 4; ++ni) {
      const int nb = n0 + wc * 64 + ni * 16 + g * 4;
      float c[4];
      if (MODE == 0) {
        const float4 bv = *(const float4*)(bias + nb);
        const float bp[4] = {bv.x, bv.y, bv.z, bv.w};
        #pragma unroll
        for (int r = 0; r < 4; ++r) {
          c[r] = acc[mi][ni][r] + bp[r];
          if (RELU) c[r] = fmaxf(c[r], 0.0f);
        }
      } else if (MODE == 1) {
        #pragma unroll
        for (int r = 0; r < 4; ++r) c[r] = fmaxf(acc[mi][ni][r], 1e-6f);
      } else {
        const float4 pv = *(const float4*)(Cf + (size_t)m * N + nb);
        const float pp[4] = {pv.x, pv.y, pv.z, pv.w};
        #pragma unroll
        for (int r = 0; r < 4; ++r) {
          float v = fmaxf(acc[mi][ni][r], 1e-6f);
          c[r] = fminf(fmaxf(0.5f * (v + pp[r]), 0.1f), 0.9f);
        }
      }
      if (CBF) {
        uint2 w;
        w.x = pack2(c[0], c[1]);
        w.y = pack2(c[2], c[3]);
        *(uint2*)(Cb + (size_t)m * N + nb) = w;
      } else {
        float4 w;
        w.x = c[0]; w.y = c[1]; w.z = c[2]; w.w = c[3];
        *(float4*)(Cf + (size_t)m * N + nb) = w;
      }
    }
  }
}

// ---------------- MFMA GEMM (N=128) with fused residual+LayerNorm ----------------
// h = LN(h + A@B^T + bias); writes h fp32 and hb bf16
template <int K>
__global__ __launch_bounds__(256) void mgemm_ln(const short* __restrict__ Ab,
                                                const short* __restrict__ Bw,
                                                const float* __restrict__ bias,
                                                float* __restrict__ hx,
                                                short* __restrict__ hb,
                                                const float* __restrict__ lng,
                                                const float* __restrict__ lnb) {
  __shared__ uint32_t Xs[128 * 32];
  __shared__ uint32_t Wls[128 * 32];
  const int t = threadIdx.x;
  const int wave = t >> 6, lane = t & 63;
  const int g = lane >> 4, p = lane & 15;
  const int wr = wave >> 1, wc = wave & 1;
  const int m0 = blockIdx.x * 128;

  f32x4 acc[4][4];
  #pragma unroll
  for (int i = 0; i < 4; ++i)
    #pragma unroll
    for (int j = 0; j < 4; ++j) acc[i][j] = (f32x4){0.f, 0.f, 0.f, 0.f};

  for (int kt = 0; kt < K; kt += 64) {
    __syncthreads();
    #pragma unroll
    for (int i = 0; i < 4; ++i) {
      const int idx = t + i * 256;
      const int row = idx >> 3, kc = idx & 7;
      const uint4 w = *(const uint4*)(Ab + (size_t)(m0 + row) * K + kt + kc * 8);
      *(uint4*)(Xs + row * 32 + ((kc ^ (row & 7)) << 2)) = w;
      const uint4 u = *(const uint4*)(Bw + (size_t)row * K + kt + kc * 8);
      *(uint4*)(Wls + row * 32 + ((kc ^ (row & 7)) << 2)) = u;
    }
    __syncthreads();
    #pragma unroll
    for (int kc32 = 0; kc32 < 2; ++kc32) {
      bf16x8 xf[4], wf[4];
      #pragma unroll
      for (int mi = 0; mi < 4; ++mi) {
        const int row = wr * 64 + mi * 16 + p;
        union { bf16x8 v; uint4 w; } u;
        u.w = *(const uint4*)(Xs + row * 32 + (((kc32 * 4 + g) ^ (row & 7)) << 2));
        xf[mi] = u.v;
      }
      #pragma unroll
      for (int ni = 0; ni < 4; ++ni) {
        const int row = wc * 64 + ni * 16 + p;
        union { bf16x8 v; uint4 w; } u;
        u.w = *(const uint4*)(Wls + row * 32 + (((kc32 * 4 + g) ^ (row & 7)) << 2));
        wf[ni] = u.v;
      }
      #pragma unroll
      for (int mi = 0; mi < 4; ++mi)
        #pragma unroll
        for (int ni = 0; ni < 4; ++ni)
          acc[mi][ni] = __builtin_amdgcn_mfma_f32_16x16x32_bf16(wf[ni], xf[mi], acc[mi][ni], 0, 0, 0);
    }
  }
  __syncthreads();

  // epilogue: residual add + cross-wave LN reduce in LDS
  float s1[4] = {0.f, 0.f, 0.f, 0.f};
  float s2[4] = {0.f, 0.f, 0.f, 0.f};
  #pragma unroll
  for (int mi = 0; mi < 4; ++mi) {
    const int m = m0 + wr * 64 + mi * 16 + p;
    #pragma unroll
    for (int ni = 0; ni < 4; ++ni) {
      const int nb = wc * 64 + ni * 16 + g * 4;
      const float4 rv = *(const float4*)(hx + (size_t)m * DD + nb);
      const float4 bv = *(const float4*)(bias + nb);
      acc[mi][ni][0] += bv.x + rv.x;
      acc[mi][ni][1] += bv.y + rv.y;
      acc[mi][ni][2] += bv.z + rv.z;
      acc[mi][ni][3] += bv.w + rv.w;
      #pragma unroll
      for (int r = 0; r < 4; ++r) {
        s1[mi] += acc[mi][ni][r];
        s2[mi] += acc[mi][ni][r] * acc[mi][ni][r];
      }
    }
  }
  float2* red = (float2*)Xs;  // 128 rows x 9 slots (8 used, padded)
  #pragma unroll
  for (int mi = 0; mi < 4; ++mi) {
    const int lr = wr * 64 + mi * 16 + p;
    red[lr * 9 + wc * 4 + g] = make_float2(s1[mi], s2[mi]);
  }
  __syncthreads();
  #pragma unroll
  for (int mi = 0; mi < 4; ++mi) {
    const int lr = wr * 64 + mi * 16 + p;
    float a = 0.f, q = 0.f;
    #pragma unroll
    for (int sslot = 0; sslot < 8; ++sslot) {
      const float2 v = red[lr * 9 + sslot];
      a += v.x; q += v.y;
    }
    const float mu = a * (1.0f / 128.0f);
    const float rs = rsqrtf(fmaxf(q * (1.0f / 128.0f) - mu * mu, 0.0f) + 1e-5f);
    const int m = m0 + lr;
    #pragma unroll
    for (int ni = 0; ni < 4; ++ni) {
      const int nb = wc * 64 + ni * 16 + g * 4;
      const float4 gv = *(const float4*)(lng + nb);
      const float4 bv = *(const float4*)(lnb + nb);
      float c[4];
      c[0] = (acc[mi][ni][0] - mu) * rs * gv.x + bv.x;
      c[1] = (acc[mi][ni][1] - mu) * rs * gv.y + bv.y;
      c[2] = (acc[mi][ni][2] - mu) * rs * gv.z + bv.z;
      c[3] = (acc[mi][ni][3] - mu) * rs * gv.w + bv.w;
      float4 w;
      w.x = c[0]; w.y = c[1]; w.z = c[2]; w.w = c[3];
      *(float4*)(hx + (size_t)m * DD + nb) = w;
      uint2 wb;
      wb.x = pack2(c[0], c[1]);
      wb.y = pack2(c[2], c[3]);
      *(uint2*)(hb + (size_t)m * DD + nb) = wb;
    }
  }
}

// ---------------- MFMA flash attention (bf16 in/out), HD=16, Q pre-scaled ----------------
__global__ __launch_bounds__(512) void attn_mfma_kernel(const short* __restrict__ qkv,
                                                        short* __restrict__ o_out) {
  const int h = blockIdx.x;
  const int b = blockIdx.y;
  const int z = blockIdx.z;
  const int t = threadIdx.x;
  const int wave = t >> 6;
  const int lane = t & 63;
  const int g = lane >> 4;
  const int p = lane & 15;

  __shared__ uint32_t Ks[512 * 8];   // 16 KB
  __shared__ uint32_t Vs[16 * 256];  // 16 KB

  const short* base = qkv + (size_t)b * SS * 384;

  { // stage K (swizzled)
    const int row = t;
    const short* kp = base + (size_t)row * 384 + DD + h * HDIM;
    const uint4 lo = *(const uint4*)kp;
    const uint4 hi = *(const uint4*)(kp + 8);
    const int blk = ((row >> 2) & 1) << 2;
    *(uint4*)(Ks + row * 8 + blk) = lo;
    *(uint4*)(Ks + row * 8 + (blk ^ 4)) = hi;
  }
  { // stage V^T (swizzled)
    const int k = t;
    const short* vp = base + (size_t)k * 384 + 2 * DD + h * HDIM;
    union { uint4 u[2]; short s[16]; } vv;
    vv.u[0] = *(const uint4*)vp;
    vv.u[1] = *(const uint4*)(vp + 8);
    const int wk = k >> 1;
    #pragma unroll
    for (int d = 0; d < 16; ++d) {
      const int word = d * 256 + (wk ^ ((d & 7) << 2));
      ((short*)(Vs + word))[k & 1] = vv.s[d];
    }
  }
  __syncthreads();

  const bf16x8 zfrag = {0, 0, 0, 0, 0, 0, 0, 0};
  const f32x4 zacc = {0.f, 0.f, 0.f, 0.f};

  #pragma unroll
  for (int qi = 0; qi < 2; ++qi) {
    const int qt = z * 16 + wave + qi * 8;
    bf16x8 qf = zfrag;
    if (g < 2) {
      const short* qp = base + (size_t)(qt * 16 + p) * 384 + h * HDIM + g * 8;
      union { bf16x8 v; uint4 w; } qu;
      qu.w = *(const uint4*)qp;
      qf = qu.v;
    }

    f32x4 o = zacc;
    float m = -1e30f, lsum = 0.0f;

    for (int kv = 0; kv < 8; ++kv) {  // 64 keys per iteration
      f32x4 s[4];
      #pragma unroll
      for (int j = 0; j < 4; ++j) {
        bf16x8 kj = zfrag;
        if (g < 2) {
          const int row = kv * 64 + j * 16 + p;
          union { bf16x8 v; uint4 w; } u;
          u.w = *(const uint4*)(Ks + row * 8 + (((g & 1) << 2) ^ (((row >> 2) & 1) << 2)));
          kj = u.v;
        }
        s[j] = __builtin_amdgcn_mfma_f32_16x16x32_bf16(kj, qf, zacc, 0, 0, 0);
      }
      float sv[16];
      float tmax = -1e30f;
      #pragma unroll
      for (int j = 0; j < 4; ++j)
        #pragma unroll
        for (int r = 0; r < 4; ++r) {
          sv[j * 4 + r] = s[j][r];
          tmax = fmaxf(tmax, s[j][r]);
        }
      tmax = fmaxf(tmax, __shfl_xor(tmax, 16));
      tmax = fmaxf(tmax, __shfl_xor(tmax, 32));
      if (!__all(tmax <= m + 8.0f)) {  // defer-max (T13)
        const float mn = fmaxf(m, tmax);
        const float sc = __expf(m - mn);
        m = mn;
        lsum *= sc;
        #pragma unroll
        for (int r = 0; r < 4; ++r) o[r] *= sc;
      }
      float ts = 0.0f;
      #pragma unroll
      for (int i = 0; i < 16; ++i) { sv[i] = __expf(sv[i] - m); ts += sv[i]; }
      ts += __shfl_xor(ts, 16);
      ts += __shfl_xor(ts, 32);
      lsum += ts;

      #pragma unroll
      for (int half = 0; half < 2; ++half) {
        const uint32_t c0 = pack2(sv[half * 8 + 0], sv[half * 8 + 1]);
        const uint32_t c1 = pack2(sv[half * 8 + 2], sv[half * 8 + 3]);
        const uint32_t c2 = pack2(sv[half * 8 + 4], sv[half * 8 + 5]);
        const uint32_t c3 = pack2(sv[half * 8 + 6], sv[half * 8 + 7]);
        const int srcA = (((2 * g) & 3) << 4) | p;
        const int srcB = (((2 * g + 1) & 3) << 4) | p;
        const uint32_t a0 = (uint32_t)__shfl((int)c0, srcA);
        const uint32_t a2 = (uint32_t)__shfl((int)c2, srcA);
        const uint32_t b0 = (uint32_t)__shfl((int)c1, srcA);
        const uint32_t b2 = (uint32_t)__shfl((int)c3, srcA);
        const uint32_t d0 = (uint32_t)__shfl((int)c0, srcB);
        const uint32_t d2 = (uint32_t)__shfl((int)c2, srcB);
        const uint32_t e0 = (uint32_t)__shfl((int)c1, srcB);
        const uint32_t e2 = (uint32_t)__shfl((int)c3, srcB);
        union { bf16x8 v; uint4 w; } pu;
        pu.w.x = (g < 2) ? a0 : a2;
        pu.w.y = (g < 2) ? b0 : b2;
        pu.w.z = (g < 2) ? d0 : d2;
        pu.w.w = (g < 2) ? e0 : e2;

        union { bf16x8 v; uint4 w; } vu;
        vu.w = *(const uint4*)(Vs + p * 256 + ((kv * 32 + half * 16 + g * 4) ^ ((p & 7) << 2)));

        o = __builtin_amdgcn_mfma_f32_16x16x32_bf16(vu.v, pu.v, o, 0, 0, 0);
      }
    }

    const float inv = 1.0f / lsum;
    uint2 w;
    w.x = pack2(o[0] * inv, o[1] * inv);
    w.y = pack2(o[2] * inv, o[3] * inv);
    *(uint2*)(o_out + ((size_t)(b * SS + qt * 16 + p)) * DD + h * HDIM + g * 4) = w;
  }
}

// ---------------- yn = normalize(sigmoid(h) * x0) rowwise -> bf16 ----------------
__global__ __launch_bounds__(256) void mask_norm_kernel(const float* __restrict__ h,
                                                        const float* __restrict__ x0,
                                                        short* __restrict__ yn) {
  const int wave = threadIdx.x >> 6;
  const int lane = threadIdx.x & 63;
  const size_t row = (size_t)blockIdx.x * 4 + wave;
  const float2 hv = ((const float2*)(h + row * DD))[lane];
  const float2 xv = ((const float2*)(x0 + row * DD))[lane];
  const float a = xv.x / (1.0f + __expf(-hv.x));
  const float c = xv.y / (1.0f + __expf(-hv.y));
  float ss = a * a + c * c;
  #pragma unroll
  for (int off = 1; off < 64; off <<= 1) ss += __shfl_xor(ss, off);
  const float inv = 1.0f / fmaxf(sqrtf(ss), 1e-12f);
  ((uint32_t*)yn)[row * 64 + lane] = pack2(a * inv, c * inv);
}

extern "C" void kernel_launch(void* const* d_in, const int* in_sizes, int n_in,
                              void* d_out, int out_size, void* d_ws, size_t ws_size,
                              hipStream_t stream) {
  const float* src  = (const float*)d_in[0];
  const float* Wqkv = (const float*)d_in[1];
  const float* bqkv = (const float*)d_in[2];
  const float* Wo   = (const float*)d_in[3];
  const float* bo   = (const float*)d_in[4];
  const float* ln1g = (const float*)d_in[5];
  const float* ln1b = (const float*)d_in[6];
  const float* W1   = (const float*)d_in[7];
  const float* b1   = (const float*)d_in[8];
  const float* W2   = (const float*)d_in[9];
  const float* b2   = (const float*)d_in[10];
  const float* ln2g = (const float*)d_in[11];
  const float* ln2b = (const float*)d_in[12];
  float* out = (float*)d_out;

  char* W = (char*)d_ws;
  const size_t MB = 1048576;
  float* x0  = (float*)(W);             // 16 MB
  float* h   = (float*)(W + 16 * MB);   // 16 MB
  short* hb  = (short*)(W + 32 * MB);   // 8 MB
  short* qkv = (short*)(W + 40 * MB);   // 24 MB
  short* ff1 = (short*)(W + 64 * MB);   // 64 MB
  short* att = (short*)(W + 128 * MB);  // 8 MB
  short* xn  = (short*)(W + 136 * MB);  // 8 MB
  short* yn  = (short*)(W + 144 * MB);  // 8 MB
  short* wqB = (short*)(W + 152 * MB);
  short* woB = wqB + (size_t)NL * 384 * DD;
  short* w1B = woB + (size_t)NL * DD * DD;
  short* w2B = w1B + (size_t)NL * FFD * DD;
  float* bq2 = (float*)(w2B + (size_t)NL * DD * FFD);

  const dim3 blk(256);
  const int ROWS = BB * SS;  // 32768

  cvt_qkv_kernel<<<(NL * 384 * 64 + 255) / 256, blk, 0, stream>>>(Wqkv, wqB);
  cvt_kernel<<<(NL * DD * DD / 2 + 255) / 256, blk, 0, stream>>>(Wo, woB, NL * DD * DD / 2);
  cvt_kernel<<<(NL * FFD * DD / 2 + 255) / 256, blk, 0, stream>>>(W1, w1B, NL * FFD * DD / 2);
  cvt_kernel<<<(NL * DD * FFD / 2 + 255) / 256, blk, 0, stream>>>(W2, w2B, NL * DD * FFD / 2);
  scale_bq_kernel<<<(NL * 384 + 255) / 256, blk, 0, stream>>>(bqkv, bq2);

  transpose_kernel<<<4096, blk, 0, stream>>>(src, x0, h, hb);
  rownorm_kernel<<<ROWS / 4, blk, 0, stream>>>(x0, xn);
  mgemm<1, false, false><<<dim3(4, 4, BB), blk, 0, stream>>>(
      xn, xn, nullptr, out, SS, SS, DD, (long)SS * DD, (long)SS * DD, (long)SS * SS);

  for (int l = 0; l < NL; ++l) {
    mgemm<0, true, false><<<dim3(3, ROWS / 128, 1), blk, 0, stream>>>(
        hb, wqB + (size_t)l * 384 * DD, bq2 + l * 384, qkv, ROWS, 384, DD, 0, 0, 0);
    attn_mfma_kernel<<<dim3(HH, BB, 2), dim3(512), 0, stream>>>(qkv, att);
    mgemm_ln<DD><<<dim3(ROWS / 128), blk, 0, stream>>>(
        att, woB + (size_t)l * DD * DD, bo + l * DD, h, hb, ln1g + l * DD, ln1b + l * DD);
    mgemm<0, true, true><<<dim3(8, ROWS / 128, 1), blk, 0, stream>>>(
        hb, w1B + (size_t)l * FFD * DD, b1 + l * FFD, ff1, ROWS, FFD, DD, 0, 0, 0);
    mgemm_ln<FFD><<<dim3(ROWS / 128), blk, 0, stream>>>(
        ff1, w2B + (size_t)l * DD * FFD, b2 + l * DD, h, hb, ln2g + l * DD, ln2b + l * DD);
  }

  mask_norm_kernel<<<ROWS / 4, blk, 0, stream>>>(h, x0, yn);
  mgemm<2, false, false><<<dim3(4, 4, BB), blk, 0, stream>>>(
      yn, yn, nullptr, out, SS, SS, DD, (long)SS * DD, (long)SS * DD, (long)SS * SS);
}

// Round 5
// 943.433 us; speedup vs baseline: 5.3330x; 1.0416x over previous
//
#include <hip/hip_runtime.h>
#include <cstdint>
#include <cstddef>

#define SS 512
#define BB 64
#define DD 128
#define HH 8
#define HDIM 16
#define FFD 1024
#define NL 6

typedef short bf16x8 __attribute__((ext_vector_type(8)));
typedef float f32x4 __attribute__((ext_vector_type(4)));

// hardware packed f32->bf16 (RNE), low16 = a, high16 = b
__device__ inline uint32_t pack2(float a, float b) {
  uint32_t r;
  asm("v_cvt_pk_bf16_f32 %0, %1, %2" : "=v"(r) : "v"(a), "v"(b));
  return r;
}

#define QSCALE 0.36067376022224085f  /* 0.25 * log2(e) */

// ---------------- fp32 -> bf16 convert (weights) ----------------
__global__ __launch_bounds__(256) void cvt_kernel(const float* __restrict__ s,
                                                  short* __restrict__ d, int n2) {
  int i = blockIdx.x * 256 + threadIdx.x;
  if (i < n2) {
    float2 v = ((const float2*)s)[i];
    ((uint32_t*)d)[i] = pack2(v.x, v.y);
  }
}

// qkv weights: scale Q rows (n<128) by 0.25*log2e (score scale folded, log2 domain)
__global__ __launch_bounds__(256) void cvt_qkv_kernel(const float* __restrict__ s,
                                                      short* __restrict__ d) {
  int i = blockIdx.x * 256 + threadIdx.x;
  if (i < NL * 384 * 64) {
    const int within = i % (384 * 64);
    const float sc = (within < 128 * 64) ? QSCALE : 1.0f;
    float2 v = ((const float2*)s)[i];
    ((uint32_t*)d)[i] = pack2(v.x * sc, v.y * sc);
  }
}

__global__ __launch_bounds__(256) void scale_bq_kernel(const float* __restrict__ s,
                                                       float* __restrict__ d) {
  int i = blockIdx.x * 256 + threadIdx.x;
  if (i < NL * 384) {
    const float sc = ((i % 384) < 128) ? QSCALE : 1.0f;
    d[i] = s[i] * sc;
  }
}

// ---------------- transpose (S,B,D) -> (B,S,D): x0 fp32, h fp32, hb bf16 ----------------
__global__ __launch_bounds__(256) void transpose_kernel(const float* __restrict__ src,
                                                        float* __restrict__ x0,
                                                        float* __restrict__ h,
                                                        short* __restrict__ hb) {
  int f = blockIdx.x * 256 + threadIdx.x;
  int b = f >> 14;
  int rem = f & 16383;
  int s = rem >> 5;
  int d4 = rem & 31;
  const float4 v = ((const float4*)src)[((size_t)s * BB + b) * 32 + d4];
  ((float4*)x0)[f] = v;
  ((float4*)h)[f] = v;
  uint2 pb;
  pb.x = pack2(v.x, v.y);
  pb.y = pack2(v.z, v.w);
  ((uint2*)hb)[f] = pb;
}

// ---------------- per-row normalize -> bf16 ----------------
__global__ __launch_bounds__(256) void rownorm_kernel(const float* __restrict__ x,
                                                      short* __restrict__ xn) {
  const int wave = threadIdx.x >> 6;
  const int lane = threadIdx.x & 63;
  const size_t row = (size_t)blockIdx.x * 4 + wave;
  const float2 v = ((const float2*)(x + row * DD))[lane];
  float ss = v.x * v.x + v.y * v.y;
  #pragma unroll
  for (int off = 1; off < 64; off <<= 1) ss += __shfl_xor(ss, off);
  const float r = rsqrtf(ss);
  ((uint32_t*)xn)[row * 64 + lane] = pack2(v.x * r, v.y * r);
}

// ---------------- MFMA GEMM: C[m,n] = epilogue(sum_k A[m,k]*B[n,k]) ----------------
// MODE 0: + bias[n], optional ReLU.  MODE 1: max(.,1e-6).  MODE 2: clip(0.5*(max(.,1e-6)+prev),0.1,0.9)
template <int MODE, bool CBF, bool RELU>
__global__ __launch_bounds__(256) void mgemm(const short* __restrict__ Ab0,
                                             const short* __restrict__ Bw,
                                             const float* __restrict__ bias,
                                             void* __restrict__ Cp,
                                             int M, int N, int K,
                                             long sA, long sB, long sC) {
  __shared__ uint32_t Xs[128 * 32];
  __shared__ uint32_t Wls[128 * 32];
  const int t = threadIdx.x;
  const int wave = t >> 6, lane = t & 63;
  const int g = lane >> 4, p = lane & 15;
  const int wr = wave >> 1, wc = wave & 1;
  const int m0 = blockIdx.y * 128, n0 = blockIdx.x * 128;
  const int z = blockIdx.z;
  const short* Ab = Ab0 + (size_t)z * sA;
  const short* Bb = Bw + (size_t)z * sB;
  float* Cf = (float*)Cp + (CBF ? (size_t)0 : (size_t)z * sC);
  short* Cb = (short*)Cp;

  f32x4 acc[4][4];
  #pragma unroll
  for (int i = 0; i < 4; ++i)
    #pragma unroll
    for (int j = 0; j < 4; ++j) acc[i][j] = (f32x4){0.f, 0.f, 0.f, 0.f};

  for (int kt = 0; kt < K; kt += 64) {
    __syncthreads();
    #pragma unroll
    for (int i = 0; i < 4; ++i) {
      const int idx = t + i * 256;
      const int row = idx >> 3, kc = idx & 7;
      const uint4 w = *(const uint4*)(Ab + (size_t)(m0 + row) * K + kt + kc * 8);
      *(uint4*)(Xs + row * 32 + ((kc ^ (row & 7)) << 2)) = w;
      const uint4 u = *(const uint4*)(Bb + (size_t)(n0 + row) * K + kt + kc * 8);
      *(uint4*)(Wls + row * 32 + ((kc ^ (row & 7)) << 2)) = u;
    }
    __syncthreads();
    #pragma unroll
    for (int kc32 = 0; kc32 < 2; ++kc32) {
      bf16x8 xf[4], wf[4];
      #pragma unroll
      for (int mi = 0; mi < 4; ++mi) {
        const int row = wr * 64 + mi * 16 + p;
        union { bf16x8 v; uint4 w; } u;
        u.w = *(const uint4*)(Xs + row * 32 + (((kc32 * 4 + g) ^ (row & 7)) << 2));
        xf[mi] = u.v;
      }
      #pragma unroll
      for (int ni = 0; ni < 4; ++ni) {
        const int row = wc * 64 + ni * 16 + p;
        union { bf16x8 v; uint4 w; } u;
        u.w = *(const uint4*)(Wls + row * 32 + (((kc32 * 4 + g) ^ (row & 7)) << 2));
        wf[ni] = u.v;
      }
      #pragma unroll
      for (int mi = 0; mi < 4; ++mi)
        #pragma unroll
        for (int ni = 0; ni < 4; ++ni)
          acc[mi][ni] = __builtin_amdgcn_mfma_f32_16x16x32_bf16(wf[ni], xf[mi], acc[mi][ni], 0, 0, 0);
    }
  }

  #pragma unroll
  for (int mi = 0; mi < 4; ++mi) {
    const int m = m0 + wr * 64 + mi * 16 + p;
    #pragma unroll
    for (int ni = 0; ni < 4; ++ni) {
      const int nb = n0 + wc * 64 + ni * 16 + g * 4;
      float c[4];
      if (MODE == 0) {
        const float4 bv = *(const float4*)(bias + nb);
        const float bp[4] = {bv.x, bv.y, bv.z, bv.w};
        #pragma unroll
        for (int r = 0; r < 4; ++r) {
          c[r] = acc[mi][ni][r] + bp[r];
          if (RELU) c[r] = fmaxf(c[r], 0.0f);
        }
      } else if (MODE == 1) {
        #pragma unroll
        for (int r = 0; r < 4; ++r) c[r] = fmaxf(acc[mi][ni][r], 1e-6f);
      } else {
        const float4 pv = *(const float4*)(Cf + (size_t)m * N + nb);
        const float pp[4] = {pv.x, pv.y, pv.z, pv.w};
        #pragma unroll
        for (int r = 0; r < 4; ++r) {
          float v = fmaxf(acc[mi][ni][r], 1e-6f);
          c[r] = fminf(fmaxf(0.5f * (v + pp[r]), 0.1f), 0.9f);
        }
      }
      if (CBF) {
        uint2 w;
        w.x = pack2(c[0], c[1]);
        w.y = pack2(c[2], c[3]);
        *(uint2*)(Cb + (size_t)m * N + nb) = w;
      } else {
        float4 w;
        w.x = c[0]; w.y = c[1]; w.z = c[2]; w.w = c[3];
        *(float4*)(Cf + (size_t)m * N + nb) = w;
      }
    }
  }
}

// ---------------- MFMA GEMM (N=128) with fused residual+LayerNorm ----------------
template <int K>
__global__ __launch_bounds__(256) void mgemm_ln(const short* __restrict__ Ab,
                                                const short* __restrict__ Bw,
                                                const float* __restrict__ bias,
                                                float* __restrict__ hx,
                                                short* __restrict__ hb,
                                                const float* __restrict__ lng,
                                                const float* __restrict__ lnb) {
  __shared__ uint32_t Xs[128 * 32];
  __shared__ uint32_t Wls[128 * 32];
  const int t = threadIdx.x;
  const int wave = t >> 6, lane = t & 63;
  const int g = lane >> 4, p = lane & 15;
  const int wr = wave >> 1, wc = wave & 1;
  const int m0 = blockIdx.x * 128;

  f32x4 acc[4][4];
  #pragma unroll
  for (int i = 0; i < 4; ++i)
    #pragma unroll
    for (int j = 0; j < 4; ++j) acc[i][j] = (f32x4){0.f, 0.f, 0.f, 0.f};

  for (int kt = 0; kt < K; kt += 64) {
    __syncthreads();
    #pragma unroll
    for (int i = 0; i < 4; ++i) {
      const int idx = t + i * 256;
      const int row = idx >> 3, kc = idx & 7;
      const uint4 w = *(const uint4*)(Ab + (size_t)(m0 + row) * K + kt + kc * 8);
      *(uint4*)(Xs + row * 32 + ((kc ^ (row & 7)) << 2)) = w;
      const uint4 u = *(const uint4*)(Bw + (size_t)row * K + kt + kc * 8);
      *(uint4*)(Wls + row * 32 + ((kc ^ (row & 7)) << 2)) = u;
    }
    __syncthreads();
    #pragma unroll
    for (int kc32 = 0; kc32 < 2; ++kc32) {
      bf16x8 xf[4], wf[4];
      #pragma unroll
      for (int mi = 0; mi < 4; ++mi) {
        const int row = wr * 64 + mi * 16 + p;
        union { bf16x8 v; uint4 w; } u;
        u.w = *(const uint4*)(Xs + row * 32 + (((kc32 * 4 + g) ^ (row & 7)) << 2));
        xf[mi] = u.v;
      }
      #pragma unroll
      for (int ni = 0; ni < 4; ++ni) {
        const int row = wc * 64 + ni * 16 + p;
        union { bf16x8 v; uint4 w; } u;
        u.w = *(const uint4*)(Wls + row * 32 + (((kc32 * 4 + g) ^ (row & 7)) << 2));
        wf[ni] = u.v;
      }
      #pragma unroll
      for (int mi = 0; mi < 4; ++mi)
        #pragma unroll
        for (int ni = 0; ni < 4; ++ni)
          acc[mi][ni] = __builtin_amdgcn_mfma_f32_16x16x32_bf16(wf[ni], xf[mi], acc[mi][ni], 0, 0, 0);
    }
  }
  __syncthreads();

  float s1[4] = {0.f, 0.f, 0.f, 0.f};
  float s2[4] = {0.f, 0.f, 0.f, 0.f};
  #pragma unroll
  for (int mi = 0; mi < 4; ++mi) {
    const int m = m0 + wr * 64 + mi * 16 + p;
    #pragma unroll
    for (int ni = 0; ni < 4; ++ni) {
      const int nb = wc * 64 + ni * 16 + g * 4;
      const float4 rv = *(const float4*)(hx + (size_t)m * DD + nb);
      const float4 bv = *(const float4*)(bias + nb);
      acc[mi][ni][0] += bv.x + rv.x;
      acc[mi][ni][1] += bv.y + rv.y;
      acc[mi][ni][2] += bv.z + rv.z;
      acc[mi][ni][3] += bv.w + rv.w;
      #pragma unroll
      for (int r = 0; r < 4; ++r) {
        s1[mi] += acc[mi][ni][r];
        s2[mi] += acc[mi][ni][r] * acc[mi][ni][r];
      }
    }
  }
  float2* red = (float2*)Xs;
  #pragma unroll
  for (int mi = 0; mi < 4; ++mi) {
    const int lr = wr * 64 + mi * 16 + p;
    red[lr * 9 + wc * 4 + g] = make_float2(s1[mi], s2[mi]);
  }
  __syncthreads();
  #pragma unroll
  for (int mi = 0; mi < 4; ++mi) {
    const int lr = wr * 64 + mi * 16 + p;
    float a = 0.f, q = 0.f;
    #pragma unroll
    for (int sslot = 0; sslot < 8; ++sslot) {
      const float2 v = red[lr * 9 + sslot];
      a += v.x; q += v.y;
    }
    const float mu = a * (1.0f / 128.0f);
    const float rs = rsqrtf(fmaxf(q * (1.0f / 128.0f) - mu * mu, 0.0f) + 1e-5f);
    const int m = m0 + lr;
    #pragma unroll
    for (int ni = 0; ni < 4; ++ni) {
      const int nb = wc * 64 + ni * 16 + g * 4;
      const float4 gv = *(const float4*)(lng + nb);
      const float4 bv = *(const float4*)(lnb + nb);
      float c[4];
      c[0] = (acc[mi][ni][0] - mu) * rs * gv.x + bv.x;
      c[1] = (acc[mi][ni][1] - mu) * rs * gv.y + bv.y;
      c[2] = (acc[mi][ni][2] - mu) * rs * gv.z + bv.z;
      c[3] = (acc[mi][ni][3] - mu) * rs * gv.w + bv.w;
      float4 w;
      w.x = c[0]; w.y = c[1]; w.z = c[2]; w.w = c[3];
      *(float4*)(hx + (size_t)m * DD + nb) = w;
      uint2 wb;
      wb.x = pack2(c[0], c[1]);
      wb.y = pack2(c[2], c[3]);
      *(uint2*)(hb + (size_t)m * DD + nb) = wb;
    }
  }
}

// ---------------- MFMA flash attention v3 ----------------
// QK^T with PERMUTED K rows so P lands directly in the PV A-fragment layout
// (zero cross-lane shuffles). Scores in log2 domain (Q pre-scaled by 0.25*log2e).
// MFMA#0 A-row r <- phys key 8*(r>>2)+(r&3); MFMA#1 <- +4.
// => lane (g,p) holds P[q=p][keys 8g..8g+7]; PV: O=mfma(A=P,B=V^T) ->
// lane (g,p) owns O[q=4g+r][d=p]; per-q stats fetched via __shfl at rare points.
__global__ __launch_bounds__(512) void attn_mfma_kernel(const short* __restrict__ qkv,
                                                        short* __restrict__ o_out) {
  const int h = blockIdx.x;
  const int b = blockIdx.y;
  const int z = blockIdx.z;
  const int t = threadIdx.x;
  const int wave = t >> 6;
  const int lane = t & 63;
  const int g = lane >> 4;
  const int p = lane & 15;

  __shared__ uint32_t Ks[512 * 8];   // 16 KB, swizzle: word ^= ((row>>3)&1)<<2
  __shared__ uint32_t Vs[16 * 256];  // 16 KB, V^T

  const short* base = qkv + (size_t)b * SS * 384;

  { // stage K
    const int row = t;
    const short* kp = base + (size_t)row * 384 + DD + h * HDIM;
    const uint4 lo = *(const uint4*)kp;
    const uint4 hi = *(const uint4*)(kp + 8);
    const int f = ((row >> 3) & 1) << 2;
    *(uint4*)(Ks + row * 8 + f) = lo;
    *(uint4*)(Ks + row * 8 + (f ^ 4)) = hi;
  }
  { // stage V^T (swizzled)
    const int k = t;
    const short* vp = base + (size_t)k * 384 + 2 * DD + h * HDIM;
    union { uint4 u[2]; short s[16]; } vv;
    vv.u[0] = *(const uint4*)vp;
    vv.u[1] = *(const uint4*)(vp + 8);
    const int wk = k >> 1;
    #pragma unroll
    for (int d = 0; d < 16; ++d) {
      const int word = d * 256 + (wk ^ ((d & 7) << 2));
      ((short*)(Vs + word))[k & 1] = vv.s[d];
    }
  }
  __syncthreads();

  const bf16x8 zfrag = {0, 0, 0, 0, 0, 0, 0, 0};
  const f32x4 zacc = {0.f, 0.f, 0.f, 0.f};

  #pragma unroll
  for (int qi = 0; qi < 2; ++qi) {
    const int qt = z * 16 + wave + qi * 8;
    bf16x8 qf = zfrag;
    if (g < 2) {
      const short* qp = base + (size_t)(qt * 16 + p) * 384 + h * HDIM + g * 8;
      union { bf16x8 v; uint4 w; } qu;
      qu.w = *(const uint4*)qp;
      qf = qu.v;
    }

    f32x4 o = zacc;
    float m = -1e30f, lsum = 0.0f;

    for (int kv = 0; kv < 16; ++kv) {  // 32 keys per iteration
      bf16x8 ka = zfrag, kb = zfrag;
      if (g < 2) {
        const int r0 = kv * 32 + 8 * (p >> 2) + (p & 3);
        const int r1 = r0 + 4;
        union { bf16x8 v; uint4 w; } u;
        u.w = *(const uint4*)(Ks + r0 * 8 + ((4 * g) ^ (((r0 >> 3) & 1) << 2)));
        ka = u.v;
        u.w = *(const uint4*)(Ks + r1 * 8 + ((4 * g) ^ (((r1 >> 3) & 1) << 2)));
        kb = u.v;
      }
      // lane (g,p): s0[r] = S[q=p][key kv*32+8g+r], s1[r] = key kv*32+8g+4+r
      const f32x4 s0 = __builtin_amdgcn_mfma_f32_16x16x32_bf16(ka, qf, zacc, 0, 0, 0);
      const f32x4 s1 = __builtin_amdgcn_mfma_f32_16x16x32_bf16(kb, qf, zacc, 0, 0, 0);

      float tmax = -1e30f;
      #pragma unroll
      for (int r = 0; r < 4; ++r) tmax = fmaxf(tmax, fmaxf(s0[r], s1[r]));
      tmax = fmaxf(tmax, __shfl_xor(tmax, 16));
      tmax = fmaxf(tmax, __shfl_xor(tmax, 32));
      if (!__all(tmax <= m + 11.0f)) {  // defer-max, log2 domain
        const float mn = fmaxf(m, tmax);
        const float sc = __builtin_amdgcn_exp2f(m - mn);
        m = mn;
        lsum *= sc;
        #pragma unroll
        for (int r = 0; r < 4; ++r) o[r] *= __shfl(sc, 4 * g + r);
      }
      float sv0[4], sv1[4];
      float ts = 0.0f;
      #pragma unroll
      for (int r = 0; r < 4; ++r) {
        sv0[r] = __builtin_amdgcn_exp2f(s0[r] - m);
        sv1[r] = __builtin_amdgcn_exp2f(s1[r] - m);
        ts += sv0[r] + sv1[r];
      }
      ts += __shfl_xor(ts, 16);
      ts += __shfl_xor(ts, 32);
      lsum += ts;

      union { bf16x8 v; uint4 w; } pu;
      pu.w.x = pack2(sv0[0], sv0[1]);
      pu.w.y = pack2(sv0[2], sv0[3]);
      pu.w.z = pack2(sv1[0], sv1[1]);
      pu.w.w = pack2(sv1[2], sv1[3]);

      union { bf16x8 v; uint4 w; } vu;
      vu.w = *(const uint4*)(Vs + p * 256 + ((kv * 16 + g * 4) ^ ((p & 7) << 2)));

      o = __builtin_amdgcn_mfma_f32_16x16x32_bf16(pu.v, vu.v, o, 0, 0, 0);
    }

    const float li = 1.0f / lsum;
    #pragma unroll
    for (int r = 0; r < 4; ++r) {
      const float inv = __shfl(li, 4 * g + r);
      const uint32_t pk = pack2(o[r] * inv, 0.0f);
      o_out[((size_t)(b * SS + qt * 16 + 4 * g + r)) * DD + h * HDIM + p] = (short)(pk & 0xffff);
    }
  }
}

// ---------------- yn = normalize(sigmoid(h) * x0) rowwise -> bf16 ----------------
__global__ __launch_bounds__(256) void mask_norm_kernel(const float* __restrict__ h,
                                                        const float* __restrict__ x0,
                                                        short* __restrict__ yn) {
  const int wave = threadIdx.x >> 6;
  const int lane = threadIdx.x & 63;
  const size_t row = (size_t)blockIdx.x * 4 + wave;
  const float2 hv = ((const float2*)(h + row * DD))[lane];
  const float2 xv = ((const float2*)(x0 + row * DD))[lane];
  const float a = xv.x / (1.0f + __expf(-hv.x));
  const float c = xv.y / (1.0f + __expf(-hv.y));
  float ss = a * a + c * c;
  #pragma unroll
  for (int off = 1; off < 64; off <<= 1) ss += __shfl_xor(ss, off);
  const float inv = 1.0f / fmaxf(sqrtf(ss), 1e-12f);
  ((uint32_t*)yn)[row * 64 + lane] = pack2(a * inv, c * inv);
}

extern "C" void kernel_launch(void* const* d_in, const int* in_sizes, int n_in,
                              void* d_out, int out_size, void* d_ws, size_t ws_size,
                              hipStream_t stream) {
  const float* src  = (const float*)d_in[0];
  const float* Wqkv = (const float*)d_in[1];
  const float* bqkv = (const float*)d_in[2];
  const float* Wo   = (const float*)d_in[3];
  const float* bo   = (const float*)d_in[4];
  const float* ln1g = (const float*)d_in[5];
  const float* ln1b = (const float*)d_in[6];
  const float* W1   = (const float*)d_in[7];
  const float* b1   = (const float*)d_in[8];
  const float* W2   = (const float*)d_in[9];
  const float* b2   = (const float*)d_in[10];
  const float* ln2g = (const float*)d_in[11];
  const float* ln2b = (const float*)d_in[12];
  float* out = (float*)d_out;

  char* W = (char*)d_ws;
  const size_t MB = 1048576;
  float* x0  = (float*)(W);
  float* h   = (float*)(W + 16 * MB);
  short* hb  = (short*)(W + 32 * MB);
  short* qkv = (short*)(W + 40 * MB);
  short* ff1 = (short*)(W + 64 * MB);
  short* att = (short*)(W + 128 * MB);
  short* xn  = (short*)(W + 136 * MB);
  short* yn  = (short*)(W + 144 * MB);
  short* wqB = (short*)(W + 152 * MB);
  short* woB = wqB + (size_t)NL * 384 * DD;
  short* w1B = woB + (size_t)NL * DD * DD;
  short* w2B = w1B + (size_t)NL * FFD * DD;
  float* bq2 = (float*)(w2B + (size_t)NL * DD * FFD);

  const dim3 blk(256);
  const int ROWS = BB * SS;

  cvt_qkv_kernel<<<(NL * 384 * 64 + 255) / 256, blk, 0, stream>>>(Wqkv, wqB);
  cvt_kernel<<<(NL * DD * DD / 2 + 255) / 256, blk, 0, stream>>>(Wo, woB, NL * DD * DD / 2);
  cvt_kernel<<<(NL * FFD * DD / 2 + 255) / 256, blk, 0, stream>>>(W1, w1B, NL * FFD * DD / 2);
  cvt_kernel<<<(NL * DD * FFD / 2 + 255) / 256, blk, 0, stream>>>(W2, w2B, NL * DD * FFD / 2);
  scale_bq_kernel<<<(NL * 384 + 255) / 256, blk, 0, stream>>>(bqkv, bq2);

  transpose_kernel<<<4096, blk, 0, stream>>>(src, x0, h, hb);
  rownorm_kernel<<<ROWS / 4, blk, 0, stream>>>(x0, xn);
  mgemm<1, false, false><<<dim3(4, 4, BB), blk, 0, stream>>>(
      xn, xn, nullptr, out, SS, SS, DD, (long)SS * DD, (long)SS * DD, (long)SS * SS);

  for (int l = 0; l < NL; ++l) {
    mgemm<0, true, false><<<dim3(3, ROWS / 128, 1), blk, 0, stream>>>(
        hb, wqB + (size_t)l * 384 * DD, bq2 + l * 384, qkv, ROWS, 384, DD, 0, 0, 0);
    attn_mfma_kernel<<<dim3(HH, BB, 2), dim3(512), 0, stream>>>(qkv, att);
    mgemm_ln<DD><<<dim3(ROWS / 128), blk, 0, stream>>>(
        att, woB + (size_t)l * DD * DD, bo + l * DD, h, hb, ln1g + l * DD, ln1b + l * DD);
    mgemm<0, true, true><<<dim3(8, ROWS / 128, 1), blk, 0, stream>>>(
        hb, w1B + (size_t)l * FFD * DD, b1 + l * FFD, ff1, ROWS, FFD, DD, 0, 0, 0);
    mgemm_ln<FFD><<<dim3(ROWS / 128), blk, 0, stream>>>(
        ff1, w2B + (size_t)l * DD * FFD, b2 + l * DD, h, hb, ln2g + l * DD, ln2b + l * DD);
  }

  mask_norm_kernel<<<ROWS / 4, blk, 0, stream>>>(h, x0, yn);
  mgemm<2, false, false><<<dim3(4, 4, BB), blk, 0, stream>>>(
      yn, yn, nullptr, out, SS, SS, DD, (long)SS * DD, (long)SS * DD, (long)SS * SS);
}